// Round 14
// baseline (153.847 us; speedup 1.0000x reference)
//
#include <hip/hip_runtime.h>
#include <hip/hip_bf16.h>
#include <math.h>

#define Bsz 2
#define Tt  2048
#define Cc  1024
#define Hh  16
#define Dd  64

typedef __attribute__((ext_vector_type(8))) short short8v;
typedef __attribute__((ext_vector_type(4))) short short4v;
typedef __attribute__((ext_vector_type(8))) _Float16 half8v;
typedef __attribute__((ext_vector_type(4))) float f32x4;
typedef __attribute__((ext_vector_type(16))) float f32x16;
typedef __attribute__((ext_vector_type(4))) unsigned int uint4v;

static __device__ __forceinline__ short f2h(float f) {
  _Float16 h = (_Float16)f;   // v_cvt_f16_f32 (RNE)
  return __builtin_bit_cast(short, h);
}
static __device__ __forceinline__ float h2f(short s) {
  _Float16 h = __builtin_bit_cast(_Float16, s);
  return (float)h;
}
static __device__ __forceinline__ void gll16(const void* g, void* l) {
  __builtin_amdgcn_global_load_lds((const __attribute__((address_space(1))) unsigned int*)g,
                                   (__attribute__((address_space(3))) unsigned int*)l, 16, 0, 0);
}

// ---------------- prepass: cast x to fp16 ----------------
__global__ void cast_x(const float* __restrict__ x, short* __restrict__ xh) {
  int t = blockIdx.x * 256 + threadIdx.x;
  const float* s = x + (size_t)t * 8;
  float4 a = *(const float4*)s, b = *(const float4*)(s + 4);
  short8v h;
  h[0] = f2h(a.x); h[1] = f2h(a.y); h[2] = f2h(a.z); h[3] = f2h(a.w);
  h[4] = f2h(b.x); h[5] = f2h(b.y); h[6] = f2h(b.z); h[7] = f2h(b.w);
  *(short8v*)(xh + (size_t)t * 8) = h;
}

// ---------------- prepass: cast + transpose W -> Wt[n][k] fp16 ----------------
__global__ __launch_bounds__(256) void cast_wT(const float* __restrict__ Wq,
                                               const float* __restrict__ Wk,
                                               const float* __restrict__ Wv,
                                               const float* __restrict__ Wo,
                                               short* __restrict__ WTh) {
  __shared__ float T[64][68];
  const int z = blockIdx.z;
  const float* W = z == 0 ? Wq : z == 1 ? Wk : z == 2 ? Wv : Wo;
  short* oh = WTh + (size_t)z * 1048576;
  const int n0 = blockIdx.x * 64, k0 = blockIdx.y * 64;
  const int tid = threadIdx.x;
#pragma unroll
  for (int i = 0; i < 4; ++i) {
    int slot = tid + i * 256;
    int r = slot >> 4, c4 = (slot & 15) << 2;
    *(float4*)&T[r][c4] = *(const float4*)(W + (size_t)(k0 + r) * Cc + n0 + c4);
  }
  __syncthreads();
#pragma unroll
  for (int i = 0; i < 2; ++i) {
    int slot = tid + i * 256;
    int nl = slot >> 3, ks = (slot & 7) << 3;
    short8v h;
#pragma unroll
    for (int e = 0; e < 8; ++e) h[e] = f2h(T[ks + e][nl]);
    *(short8v*)(oh + (size_t)(n0 + nl) * Cc + k0 + ks) = h;
  }
}

// ================= 128x128 fp16 GEMM core (single-pass MFMA) =================
__device__ __forceinline__ void core128h(const short* __restrict__ Ah,
                                         const short* __restrict__ Bh,
                                         short* AhL, short* BhL,
                                         int row0, int col0, int wv, int lane, f32x4 acc[4][4]) {
  const int l15 = lane & 15, g = lane >> 4;
  const int wr = wv >> 1, wc = wv & 1;

  const int srow0 = wv * 32 + (lane >> 2);
  const int srow1 = srow0 + 16;
  const int sch0 = ((lane & 3) ^ ((lane >> 2) & 3)) << 3;
  const size_t aoff0 = (size_t)(row0 + srow0) * Cc + sch0;
  const size_t aoff1 = (size_t)(row0 + srow1) * Cc + sch0;
  const size_t boff0 = (size_t)(col0 + srow0) * Cc + sch0;
  const size_t boff1 = (size_t)(col0 + srow1) * Cc + sch0;
  short* dA0 = AhL + wv * 1024;  short* dA1 = dA0 + 512;
  short* dB0 = BhL + wv * 1024;  short* dB1 = dB0 + 512;

  int aL[4], bL[4];
#pragma unroll
  for (int m = 0; m < 4; ++m) aL[m] = (wr * 64 + m * 16 + l15) * 32 + ((g ^ (l15 & 3)) << 3);
#pragma unroll
  for (int n = 0; n < 4; ++n) bL[n] = (wc * 64 + n * 16 + l15) * 32 + ((g ^ (l15 & 3)) << 3);

  for (int k0 = 0; k0 < Cc; k0 += 32) {
    __syncthreads();
    gll16(Ah + aoff0 + k0, dA0);
    gll16(Ah + aoff1 + k0, dA1);
    gll16(Bh + boff0 + k0, dB0);
    gll16(Bh + boff1 + k0, dB1);
    __syncthreads();
    half8v a[4], b[4];
#pragma unroll
    for (int m = 0; m < 4; ++m) a[m] = __builtin_bit_cast(half8v, *(short8v*)&AhL[aL[m]]);
#pragma unroll
    for (int n = 0; n < 4; ++n) b[n] = __builtin_bit_cast(half8v, *(short8v*)&BhL[bL[n]]);
#pragma unroll
    for (int m = 0; m < 4; ++m)
#pragma unroll
      for (int n = 0; n < 4; ++n)
        acc[m][n] = __builtin_amdgcn_mfma_f32_16x16x32_f16(a[m], b[n], acc[m][n], 0, 0, 0);
  }
}

// ---------------- QKV projection GEMM (fp16), rope fused, V transposed ----------------
__global__ __launch_bounds__(256, 3) void gemm_qkv(const short* __restrict__ xh,
                                                   const short* __restrict__ WTh,
                                                   const float* __restrict__ bq,
                                                   const float* __restrict__ bk,
                                                   const float* __restrict__ bv,
                                                   short* __restrict__ qb,
                                                   short* __restrict__ kb,
                                                   short* __restrict__ vb) {
  __shared__ short AhL[4096], BhL[4096];
  const int mode = blockIdx.y;
  const short* Bh = WTh + (size_t)mode * 1048576;
  const float* bias = mode == 0 ? bq : mode == 1 ? bk : bv;
  short* Y = mode == 0 ? qb : mode == 1 ? kb : vb;

  const int bid = blockIdx.x;
  const int nid = ((bid & 7) << 5) | (bid >> 3);
  const int row0 = (nid >> 3) * 128, col0 = (nid & 7) * 128;
  const int lane = threadIdx.x & 63, wv = threadIdx.x >> 6;
  const int l15 = lane & 15, g = lane >> 4;
  const int wr = wv >> 1, wc = wv & 1;

  f32x4 acc[4][4];
#pragma unroll
  for (int m = 0; m < 4; ++m)
#pragma unroll
    for (int n = 0; n < 4; ++n) acc[m][n] = (f32x4){0.f, 0.f, 0.f, 0.f};

  core128h(xh, Bh, AhL, BhL, row0, col0, wv, lane, acc);

  const int cbase = col0 + wc * 64;
  const int h = cbase >> 6;
  if (mode < 2) {
    const float scale = (mode == 0) ? 0.18033688f : 1.0f;   // 1/8 * log2(e) folded for Q
#pragma unroll
    for (int n = 0; n < 2; ++n) {
      const int d = n * 16 + l15;
      const float b0 = bias[cbase + d], b1 = bias[cbase + d + 32];
      const float inv = exp2f(-(float)d * (13.2877123795494f / 32.f));
#pragma unroll
      for (int m = 0; m < 4; ++m)
#pragma unroll
        for (int rr = 0; rr < 4; ++rr) {
          int R = row0 + wr * 64 + m * 16 + g * 4 + rr;
          int bI = R >> 11, t = R & (Tt - 1);
          float sn, cs;
          sincosf((float)t * inv, &sn, &cs);
          float v0 = acc[m][n][rr] + b0, v1 = acc[m][n + 2][rr] + b1;
          size_t base = (((size_t)(bI * Hh + h) * Tt + t) << 6) + d;
          Y[base]      = f2h((v0 * cs - v1 * sn) * scale);
          Y[base + 32] = f2h((v1 * cs + v0 * sn) * scale);
        }
    }
  } else {
    // V: write transposed [B,H,D,T] fp16
#pragma unroll
    for (int n = 0; n < 2; ++n) {
      const int d = n * 16 + l15;
      const float b0 = bias[cbase + d], b1 = bias[cbase + d + 32];
#pragma unroll
      for (int m = 0; m < 4; ++m) {
        int R = row0 + wr * 64 + m * 16 + g * 4;
        int bI = R >> 11, t = R & (Tt - 1);
        short4v s0, s1;
#pragma unroll
        for (int rr = 0; rr < 4; ++rr) {
          s0[rr] = f2h(acc[m][n][rr] + b0);
          s1[rr] = f2h(acc[m][n + 2][rr] + b1);
        }
        size_t base = ((size_t)(bI * Hh + h) * Dd);
        *(short4v*)(Y + (base + d) * Tt + t)      = s0;
        *(short4v*)(Y + (base + d + 32) * Tt + t) = s1;
      }
    }
  }
}

// ---------------- final output GEMM (fp16 core, fp32 out) ----------------
__global__ __launch_bounds__(256, 3) void gemm_out(const short* __restrict__ ah,
                                                   const short* __restrict__ WTo,
                                                   const float* __restrict__ bias,
                                                   float* __restrict__ Y) {
  __shared__ short AhL[4096], BhL[4096];
  const int bid = blockIdx.x;
  const int nid = ((bid & 7) << 5) | (bid >> 3);
  const int row0 = (nid >> 3) * 128, col0 = (nid & 7) * 128;
  const int lane = threadIdx.x & 63, wv = threadIdx.x >> 6;
  const int l15 = lane & 15, g = lane >> 4;
  const int wr = wv >> 1, wc = wv & 1;

  f32x4 acc[4][4];
#pragma unroll
  for (int m = 0; m < 4; ++m)
#pragma unroll
    for (int n = 0; n < 4; ++n) acc[m][n] = (f32x4){0.f, 0.f, 0.f, 0.f};

  core128h(ah, WTo, AhL, BhL, row0, col0, wv, lane, acc);

  const int cbase = col0 + wc * 64;
#pragma unroll
  for (int n = 0; n < 2; ++n) {
    const int ccol = cbase + n * 16 + l15;
    const float b0 = bias[ccol], b1 = bias[ccol + 32];
#pragma unroll
    for (int m = 0; m < 4; ++m)
#pragma unroll
      for (int rr = 0; rr < 4; ++rr) {
        int R = row0 + wr * 64 + m * 16 + g * 4 + rr;
        Y[(size_t)R * Cc + ccol]      = acc[m][n][rr] + b0;
        Y[(size_t)R * Cc + ccol + 32] = acc[m][n + 2][rr] + b1;
      }
  }
}

// ================= MFMA flash attention v11: wave-private, ZERO barriers =========
// Each query sub-tile = its own 1-wave block (grid 3456 = 8 xcd x 4 bh x 27 jobs
// x 4 subtiles; job-mates share an XCD for K/V L2 reuse). Wave-private LDS
// (K 4KB + V 4KB, double-buffered, 16KB/block -> 10 blocks/CU). Per chunk:
// issue 8 glls for chunk c+1, s_waitcnt vmcnt(8) (chunk c's loads are the only
// older ones -> exact guard, prefetch never drained), compute, flip. No
// s_barrier anywhere: stalled waves yield the SIMD to ~9 other independent waves.
static __device__ const int JQ[27] = {11, 0,0, 1,1, 2,2, 3,3, 4,4, 12, 5,5,
                                      6,6, 13, 7,7, 8,8, 14, 9,9, 15, 10,10};
static __device__ const int JK[27] = {0, 0,1, 0,1, 0,1, 0,1, 0,1, 0, 0,1,
                                      0,1, 0, 0,1, 0,1, 0, 0,1, 0, 0,1};

__global__ __launch_bounds__(64, 4) void attn_mfma(const short* __restrict__ q,
                                                   const short* __restrict__ k,
                                                   const short* __restrict__ vT,
                                                   short* __restrict__ ah,
                                                   float* __restrict__ yb,
                                                   float* __restrict__ side) {
  const int n = blockIdx.x;           // 3456
  const int xcd = n & 7;
  const int t7 = n >> 3;              // 0..431
  const int bhj = t7 / 108;
  const int rem = t7 - bhj * 108;
  const int j = rem >> 2;
  const int qs = rem & 3;
  const int bh = xcd * 4 + bhj;
  const int Q = JQ[j];
  const int kh = JK[j];
  const int split = (Q <= 10);
  const int q0 = Q * 128;

  const int lane = threadIdx.x;       // 0..63
  const int l31 = lane & 31;
  const int hb = lane >> 5;
  const int qbase = q0 + qs * 32;
  const int tq = qbase + l31;

  const short* qgb = q + (size_t)bh * Tt * Dd;
  const short* kgb = k + (size_t)bh * Tt * Dd;
  const short* vgb = vT + (size_t)bh * Dd * Tt;

  // Q fragments: MFMA i covers dims 16i + 8hb..+7 (1/8*log2e folded)
  const short* qp = qgb + (size_t)tq * Dd + 8 * hb;
  half8v qf[4];
#pragma unroll
  for (int i = 0; i < 4; ++i) qf[i] = __builtin_bit_cast(half8v, *(const short8v*)(qp + 16 * i));

  __shared__ short Klds[2][2048];   // [buf][32 keys x 64 dims], swizzled
  __shared__ short Vt[2][2048];     // [buf][64 dims x 32 keys], swizzled

  // K staging: gll g covers key rows 8g..8g+7; lane -> row 8g+(lane>>3),
  // phys chunk lane&7, source log chunk (lane&7)^(lane>>3)
  const int ksrc = (lane >> 3) * Dd + (((lane & 7) ^ (lane >> 3)) << 3);
  // V staging: gll g covers dim rows 16g..16g+15; lane -> row 16g+(lane>>2),
  // phys chunk lane&3, source log chunk ((lane&3)-((lane>>3)&3))&3
  const int vlog = ((lane & 3) - ((lane >> 3) & 3)) & 3;
  const int vsrc = (lane >> 2) * Tt + 8 * vlog;

  // K fragment read offsets (row l31, log chunk 2i+hb, phys = ^ (l31&7))
  int koff[4];
#pragma unroll
  for (int i = 0; i < 4; ++i) koff[i] = l31 * 64 + (((2 * i + hb) ^ (l31 & 7)) << 3);
  // V fragment read offsets (rows l31 / 32+l31; log chunks hb and 2+hb)
  const int rsw = (l31 >> 1) & 3;
  const int p0 = (hb + rsw) & 3;
  const int p1 = (2 + hb + rsw) & 3;
  const int voff00 = l31 * 32 + p0 * 8;
  const int voff01 = l31 * 32 + p1 * 8;
  const int voff10 = (32 + l31) * 32 + p0 * 8;
  const int voff11 = (32 + l31) * 32 + p1 * 8;

  f32x16 oacc[2];
#pragma unroll
  for (int t = 0; t < 2; ++t)
#pragma unroll
    for (int r = 0; r < 16; ++r) oacc[t][r] = 0.f;
  float lrun = 0.f;

  const int cs0 = (q0 >= 512) ? (q0 - 511) : 0;
  const int cstart = cs0 & ~31;
  const int nch_b = (Tt - cstart) >> 5;
  const int lower = (nch_b + 1) >> 1;
  const int mystart = cstart + ((split && kh) ? (lower << 5) : 0);
  const int myn = split ? (kh ? nch_b - lower : lower) : nch_b;

  // ---- prologue: stage chunk 0 into buf 0 (8 glls) ----
#pragma unroll
  for (int g = 0; g < 4; ++g) {
    gll16(kgb + (size_t)mystart * Dd + g * 8 * Dd + ksrc, &Klds[0][g * 512]);
    gll16(vgb + (size_t)g * 16 * Tt + vsrc + mystart, &Vt[0][g * 512]);
  }

  int cur = 0;
  for (int ci = 0; ci < myn; ++ci) {
    const int jt = mystart + (ci << 5);

    // issue chunk ci+1's 8 glls into the other buffer, then wait ONLY for
    // chunk ci's loads (the 8 newest stay in flight)
    if (ci + 1 < myn) {
#pragma unroll
      for (int g = 0; g < 4; ++g) {
        gll16(kgb + (size_t)(jt + 32) * Dd + g * 8 * Dd + ksrc, &Klds[cur ^ 1][g * 512]);
        gll16(vgb + (size_t)g * 16 * Tt + vsrc + (jt + 32), &Vt[cur ^ 1][g * 512]);
      }
      asm volatile("s_waitcnt vmcnt(8)" ::: "memory");
    } else {
      asm volatile("s_waitcnt vmcnt(0)" ::: "memory");
    }
    __builtin_amdgcn_sched_barrier(0);

    // ---- QK^T from private LDS ----
    const short* kbuf = &Klds[cur][0];
    f32x16 se;
#pragma unroll
    for (int r = 0; r < 16; ++r) se[r] = 0.f;
    __builtin_amdgcn_s_setprio(1);
#pragma unroll
    for (int i = 0; i < 4; ++i) {
      half8v kf = __builtin_bit_cast(half8v, *(short8v*)&kbuf[koff[i]]);
      se = __builtin_amdgcn_mfma_f32_32x32x16_f16(kf, qf[i], se, 0, 0, 0);
    }
    __builtin_amdgcn_s_setprio(0);

    if (jt < qbase - 480) {   // boundary: window mask
      int th = tq - 511 - jt;
#pragma unroll
      for (int r = 0; r < 16; ++r) {
        int row = (r & 3) + 8 * (r >> 2) + 4 * hb;
        if (row < th) se[r] = -1e30f;
      }
    }

    // ---- no-max softmax: p = exp2(se) directly (|se| <= ~9.3 by C-S bound) ----
    float p[16], psum = 0.f;
#pragma unroll
    for (int r = 0; r < 16; ++r) { p[r] = exp2f(se[r]); psum += p[r]; }
    psum += __shfl_xor(psum, 32);
    lrun += psum;

    // ---- pack to fp16 pairs; half-wave exchange via v_permlane32_swap ----
    unsigned pk[8];
#pragma unroll
    for (int i = 0; i < 8; ++i)
      pk[i] = __builtin_bit_cast(unsigned, __builtin_amdgcn_cvt_pkrtz(p[2 * i], p[2 * i + 1]));
    asm volatile("v_permlane32_swap_b32 %0, %1" : "+v"(pk[0]), "+v"(pk[2]));
    asm volatile("v_permlane32_swap_b32 %0, %1" : "+v"(pk[1]), "+v"(pk[3]));
    asm volatile("v_permlane32_swap_b32 %0, %1" : "+v"(pk[4]), "+v"(pk[6]));
    asm volatile("v_permlane32_swap_b32 %0, %1" : "+v"(pk[5]), "+v"(pk[7]));
    uint4v f0, f1;
    f0[0] = pk[0]; f0[1] = pk[1]; f0[2] = pk[2]; f0[3] = pk[3];
    f1[0] = pk[4]; f1[1] = pk[5]; f1[2] = pk[6]; f1[3] = pk[7];
    half8v pf0 = __builtin_bit_cast(half8v, f0);
    half8v pf1 = __builtin_bit_cast(half8v, f1);

    // ---- PV from private LDS V^T ----
    half8v v00 = __builtin_bit_cast(half8v, *(short8v*)&Vt[cur][voff00]);
    half8v v01 = __builtin_bit_cast(half8v, *(short8v*)&Vt[cur][voff01]);
    half8v v10 = __builtin_bit_cast(half8v, *(short8v*)&Vt[cur][voff10]);
    half8v v11 = __builtin_bit_cast(half8v, *(short8v*)&Vt[cur][voff11]);
    __builtin_amdgcn_s_setprio(1);
    oacc[0] = __builtin_amdgcn_mfma_f32_32x32x16_f16(v00, pf0, oacc[0], 0, 0, 0);
    oacc[0] = __builtin_amdgcn_mfma_f32_32x32x16_f16(v01, pf1, oacc[0], 0, 0, 0);
    oacc[1] = __builtin_amdgcn_mfma_f32_32x32x16_f16(v10, pf0, oacc[1], 0, 0, 0);
    oacc[1] = __builtin_amdgcn_mfma_f32_32x32x16_f16(v11, pf1, oacc[1], 0, 0, 0);
    __builtin_amdgcn_s_setprio(0);

    cur ^= 1;   // no barrier: wave-private buffers
  }

  // ---- epilogue ----
  const float invl = 1.f / lrun;
  const int row = bh * Tt + tq;
  if (split && hb == 0) side[kh * 65536 + row] = lrun;
  const int bI = bh >> 4, hd = bh & 15;
  if (!split || kh == 0) {
    short* op = ah + ((size_t)(bI * Tt + tq)) * Cc + hd * Dd;
#pragma unroll
    for (int t = 0; t < 2; ++t)
#pragma unroll
      for (int rq = 0; rq < 4; ++rq) {
        short4v hv;
#pragma unroll
        for (int rr = 0; rr < 4; ++rr) hv[rr] = f2h(oacc[t][4 * rq + rr] * invl);
        *(short4v*)(op + 32 * t + 8 * rq + 4 * hb) = hv;
      }
  } else {
    float* yp = yb + (size_t)row * 64;
#pragma unroll
    for (int t = 0; t < 2; ++t)
#pragma unroll
      for (int rq = 0; rq < 4; ++rq) {
        f32x4 o4;
#pragma unroll
        for (int rr = 0; rr < 4; ++rr) o4[rr] = oacc[t][4 * rq + rr] * invl;
        *(f32x4*)(yp + 32 * t + 8 * rq + 4 * hb) = o4;
      }
  }
}

// ---------------- merge the two key-halves for split tiles (tq < 1408) ----------------
__global__ __launch_bounds__(256) void attn_merge(short* __restrict__ ah,
                                                  const float* __restrict__ yb,
                                                  const float* __restrict__ side) {
  const int bh = blockIdx.y;                         // 0..31
  const int idx = blockIdx.x * 256 + threadIdx.x;    // [0, 5632)
  const int tq = idx >> 2;                           // [0, 1408)
  const int qd = (idx & 3) << 4;
  const int row = bh * Tt + tq;
  const float l0 = side[row], l1 = side[65536 + row];
  const float inv = 1.f / (l0 + l1);
  const float a0 = l0 * inv, a1 = l1 * inv;

  const int bI = bh >> 4, hd = bh & 15;
  short* op = ah + ((size_t)(bI * Tt + tq)) * Cc + hd * Dd + qd;
  const float* yp = yb + (size_t)row * 64 + qd;

  short8v h0 = *(short8v*)op, h1 = *(short8v*)(op + 8);
  short8v o0, o1;
#pragma unroll
  for (int e = 0; e < 8; ++e) o0[e] = f2h(a0 * h2f(h0[e]) + a1 * yp[e]);
#pragma unroll
  for (int e = 0; e < 8; ++e) o1[e] = f2h(a0 * h2f(h1[e]) + a1 * yp[8 + e]);
  *(short8v*)op = o0;
  *(short8v*)(op + 8) = o1;
}

extern "C" void kernel_launch(void* const* d_in, const int* in_sizes, int n_in,
                              void* d_out, int out_size, void* d_ws, size_t ws_size,
                              hipStream_t stream) {
  const float* x  = (const float*)d_in[0];
  const float* Wq = (const float*)d_in[1];
  const float* bq = (const float*)d_in[2];
  const float* Wk = (const float*)d_in[3];
  const float* bk = (const float*)d_in[4];
  const float* Wv = (const float*)d_in[5];
  const float* bv = (const float*)d_in[6];
  const float* Wo = (const float*)d_in[7];
  const float* bo = (const float*)d_in[8];

  short* ws16 = (short*)d_ws;
  short* xh  = ws16;                  // 8MB fp16 x
  short* WTh = ws16 + 4194304;        // 8MB: Wq,Wk,Wv,Wo transposed fp16
  short* qb  = ws16 + 8388608;        // 8MB fp16 [B,H,T,D]
  short* kb  = ws16 + 12582912;       // 8MB fp16 [B,H,T,D]
  short* vb  = ws16 + 16777216;       // 8MB fp16 [B,H,D,T] (V transposed)
  short* ah  = ws16 + 20971520;       // 8MB fp16 attn out [B,T,C]
  float* yb   = (float*)(ws16 + 25165824);  // 16.78MB fp32 kh=1 partials [65536][64]
  float* side = yb + 4194304;               // 0.5MB: [kh][65536] = l

  cast_x<<<2048, 256, 0, stream>>>(x, xh);
  cast_wT<<<dim3(16, 16, 4), 256, 0, stream>>>(Wq, Wk, Wv, Wo, WTh);

  gemm_qkv<<<dim3(256, 3), 256, 0, stream>>>(xh, WTh, bq, bk, bv, qb, kb, vb);

  attn_mfma<<<3456, 64, 0, stream>>>(qb, kb, vb, ah, yb, side);
  attn_merge<<<dim3(22, 32), 256, 0, stream>>>(ah, yb, side);

  gemm_out<<<256, 256, 0, stream>>>(ah, WTh + 3 * 1048576, bo, (float*)d_out);
}

// Round 15
// 134.192 us; speedup vs baseline: 1.1465x; 1.1465x over previous
//
#include <hip/hip_runtime.h>
#include <hip/hip_bf16.h>
#include <math.h>

#define Bsz 2
#define Tt  2048
#define Cc  1024
#define Hh  16
#define Dd  64

typedef __attribute__((ext_vector_type(8))) short short8v;
typedef __attribute__((ext_vector_type(4))) short short4v;
typedef __attribute__((ext_vector_type(8))) _Float16 half8v;
typedef __attribute__((ext_vector_type(4))) float f32x4;
typedef __attribute__((ext_vector_type(16))) float f32x16;
typedef __attribute__((ext_vector_type(4))) unsigned int uint4v;

static __device__ __forceinline__ short f2h(float f) {
  _Float16 h = (_Float16)f;   // v_cvt_f16_f32 (RNE)
  return __builtin_bit_cast(short, h);
}
static __device__ __forceinline__ float h2f(short s) {
  _Float16 h = __builtin_bit_cast(_Float16, s);
  return (float)h;
}
static __device__ __forceinline__ void gll16(const void* g, void* l) {
  __builtin_amdgcn_global_load_lds((const __attribute__((address_space(1))) unsigned int*)g,
                                   (__attribute__((address_space(3))) unsigned int*)l, 16, 0, 0);
}

// ---------------- prepass: cast x to fp16 ----------------
__global__ void cast_x(const float* __restrict__ x, short* __restrict__ xh) {
  int t = blockIdx.x * 256 + threadIdx.x;
  const float* s = x + (size_t)t * 8;
  float4 a = *(const float4*)s, b = *(const float4*)(s + 4);
  short8v h;
  h[0] = f2h(a.x); h[1] = f2h(a.y); h[2] = f2h(a.z); h[3] = f2h(a.w);
  h[4] = f2h(b.x); h[5] = f2h(b.y); h[6] = f2h(b.z); h[7] = f2h(b.w);
  *(short8v*)(xh + (size_t)t * 8) = h;
}

// ---------------- prepass: cast + transpose W -> Wt[n][k] fp16 ----------------
__global__ __launch_bounds__(256) void cast_wT(const float* __restrict__ Wq,
                                               const float* __restrict__ Wk,
                                               const float* __restrict__ Wv,
                                               const float* __restrict__ Wo,
                                               short* __restrict__ WTh) {
  __shared__ float T[64][68];
  const int z = blockIdx.z;
  const float* W = z == 0 ? Wq : z == 1 ? Wk : z == 2 ? Wv : Wo;
  short* oh = WTh + (size_t)z * 1048576;
  const int n0 = blockIdx.x * 64, k0 = blockIdx.y * 64;
  const int tid = threadIdx.x;
#pragma unroll
  for (int i = 0; i < 4; ++i) {
    int slot = tid + i * 256;
    int r = slot >> 4, c4 = (slot & 15) << 2;
    *(float4*)&T[r][c4] = *(const float4*)(W + (size_t)(k0 + r) * Cc + n0 + c4);
  }
  __syncthreads();
#pragma unroll
  for (int i = 0; i < 2; ++i) {
    int slot = tid + i * 256;
    int nl = slot >> 3, ks = (slot & 7) << 3;
    short8v h;
#pragma unroll
    for (int e = 0; e < 8; ++e) h[e] = f2h(T[ks + e][nl]);
    *(short8v*)(oh + (size_t)(n0 + nl) * Cc + k0 + ks) = h;
  }
}

// ================= 128x128 fp16 GEMM core (single-pass MFMA) =================
__device__ __forceinline__ void core128h(const short* __restrict__ Ah,
                                         const short* __restrict__ Bh,
                                         short* AhL, short* BhL,
                                         int row0, int col0, int wv, int lane, f32x4 acc[4][4]) {
  const int l15 = lane & 15, g = lane >> 4;
  const int wr = wv >> 1, wc = wv & 1;

  const int srow0 = wv * 32 + (lane >> 2);
  const int srow1 = srow0 + 16;
  const int sch0 = ((lane & 3) ^ ((lane >> 2) & 3)) << 3;
  const size_t aoff0 = (size_t)(row0 + srow0) * Cc + sch0;
  const size_t aoff1 = (size_t)(row0 + srow1) * Cc + sch0;
  const size_t boff0 = (size_t)(col0 + srow0) * Cc + sch0;
  const size_t boff1 = (size_t)(col0 + srow1) * Cc + sch0;
  short* dA0 = AhL + wv * 1024;  short* dA1 = dA0 + 512;
  short* dB0 = BhL + wv * 1024;  short* dB1 = dB0 + 512;

  int aL[4], bL[4];
#pragma unroll
  for (int m = 0; m < 4; ++m) aL[m] = (wr * 64 + m * 16 + l15) * 32 + ((g ^ (l15 & 3)) << 3);
#pragma unroll
  for (int n = 0; n < 4; ++n) bL[n] = (wc * 64 + n * 16 + l15) * 32 + ((g ^ (l15 & 3)) << 3);

  for (int k0 = 0; k0 < Cc; k0 += 32) {
    __syncthreads();
    gll16(Ah + aoff0 + k0, dA0);
    gll16(Ah + aoff1 + k0, dA1);
    gll16(Bh + boff0 + k0, dB0);
    gll16(Bh + boff1 + k0, dB1);
    __syncthreads();
    half8v a[4], b[4];
#pragma unroll
    for (int m = 0; m < 4; ++m) a[m] = __builtin_bit_cast(half8v, *(short8v*)&AhL[aL[m]]);
#pragma unroll
    for (int n = 0; n < 4; ++n) b[n] = __builtin_bit_cast(half8v, *(short8v*)&BhL[bL[n]]);
#pragma unroll
    for (int m = 0; m < 4; ++m)
#pragma unroll
      for (int n = 0; n < 4; ++n)
        acc[m][n] = __builtin_amdgcn_mfma_f32_16x16x32_f16(a[m], b[n], acc[m][n], 0, 0, 0);
  }
}

// ---------------- QKV projection GEMM (fp16), rope fused, V transposed ----------------
__global__ __launch_bounds__(256, 3) void gemm_qkv(const short* __restrict__ xh,
                                                   const short* __restrict__ WTh,
                                                   const float* __restrict__ bq,
                                                   const float* __restrict__ bk,
                                                   const float* __restrict__ bv,
                                                   short* __restrict__ qb,
                                                   short* __restrict__ kb,
                                                   short* __restrict__ vb) {
  __shared__ short AhL[4096], BhL[4096];
  const int mode = blockIdx.y;
  const short* Bh = WTh + (size_t)mode * 1048576;
  const float* bias = mode == 0 ? bq : mode == 1 ? bk : bv;
  short* Y = mode == 0 ? qb : mode == 1 ? kb : vb;

  const int bid = blockIdx.x;
  const int nid = ((bid & 7) << 5) | (bid >> 3);
  const int row0 = (nid >> 3) * 128, col0 = (nid & 7) * 128;
  const int lane = threadIdx.x & 63, wv = threadIdx.x >> 6;
  const int l15 = lane & 15, g = lane >> 4;
  const int wr = wv >> 1, wc = wv & 1;

  f32x4 acc[4][4];
#pragma unroll
  for (int m = 0; m < 4; ++m)
#pragma unroll
    for (int n = 0; n < 4; ++n) acc[m][n] = (f32x4){0.f, 0.f, 0.f, 0.f};

  core128h(xh, Bh, AhL, BhL, row0, col0, wv, lane, acc);

  const int cbase = col0 + wc * 64;
  const int h = cbase >> 6;
  if (mode < 2) {
    const float scale = (mode == 0) ? 0.18033688f : 1.0f;   // 1/8 * log2(e) folded for Q
#pragma unroll
    for (int n = 0; n < 2; ++n) {
      const int d = n * 16 + l15;
      const float b0 = bias[cbase + d], b1 = bias[cbase + d + 32];
      const float inv = exp2f(-(float)d * (13.2877123795494f / 32.f));
#pragma unroll
      for (int m = 0; m < 4; ++m)
#pragma unroll
        for (int rr = 0; rr < 4; ++rr) {
          int R = row0 + wr * 64 + m * 16 + g * 4 + rr;
          int bI = R >> 11, t = R & (Tt - 1);
          float sn, cs;
          sincosf((float)t * inv, &sn, &cs);
          float v0 = acc[m][n][rr] + b0, v1 = acc[m][n + 2][rr] + b1;
          size_t base = (((size_t)(bI * Hh + h) * Tt + t) << 6) + d;
          Y[base]      = f2h((v0 * cs - v1 * sn) * scale);
          Y[base + 32] = f2h((v1 * cs + v0 * sn) * scale);
        }
    }
  } else {
    // V: write transposed [B,H,D,T] fp16
#pragma unroll
    for (int n = 0; n < 2; ++n) {
      const int d = n * 16 + l15;
      const float b0 = bias[cbase + d], b1 = bias[cbase + d + 32];
#pragma unroll
      for (int m = 0; m < 4; ++m) {
        int R = row0 + wr * 64 + m * 16 + g * 4;
        int bI = R >> 11, t = R & (Tt - 1);
        short4v s0, s1;
#pragma unroll
        for (int rr = 0; rr < 4; ++rr) {
          s0[rr] = f2h(acc[m][n][rr] + b0);
          s1[rr] = f2h(acc[m][n + 2][rr] + b1);
        }
        size_t base = ((size_t)(bI * Hh + h) * Dd);
        *(short4v*)(Y + (base + d) * Tt + t)      = s0;
        *(short4v*)(Y + (base + d + 32) * Tt + t) = s1;
      }
    }
  }
}

// ---------------- final output GEMM (fp16 core, fp32 out) ----------------
__global__ __launch_bounds__(256, 3) void gemm_out(const short* __restrict__ ah,
                                                   const short* __restrict__ WTo,
                                                   const float* __restrict__ bias,
                                                   float* __restrict__ Y) {
  __shared__ short AhL[4096], BhL[4096];
  const int bid = blockIdx.x;
  const int nid = ((bid & 7) << 5) | (bid >> 3);
  const int row0 = (nid >> 3) * 128, col0 = (nid & 7) * 128;
  const int lane = threadIdx.x & 63, wv = threadIdx.x >> 6;
  const int l15 = lane & 15, g = lane >> 4;
  const int wr = wv >> 1, wc = wv & 1;

  f32x4 acc[4][4];
#pragma unroll
  for (int m = 0; m < 4; ++m)
#pragma unroll
    for (int n = 0; n < 4; ++n) acc[m][n] = (f32x4){0.f, 0.f, 0.f, 0.f};

  core128h(ah, WTo, AhL, BhL, row0, col0, wv, lane, acc);

  const int cbase = col0 + wc * 64;
#pragma unroll
  for (int n = 0; n < 2; ++n) {
    const int ccol = cbase + n * 16 + l15;
    const float b0 = bias[ccol], b1 = bias[ccol + 32];
#pragma unroll
    for (int m = 0; m < 4; ++m)
#pragma unroll
      for (int rr = 0; rr < 4; ++rr) {
        int R = row0 + wr * 64 + m * 16 + g * 4 + rr;
        Y[(size_t)R * Cc + ccol]      = acc[m][n][rr] + b0;
        Y[(size_t)R * Cc + ccol + 32] = acc[m][n + 2][rr] + b1;
      }
  }
}

// ================= MFMA flash attention v12: r12 structure, KVBLK=64 =============
// Same 4-wave 864-block layout, gll+swizzle staging, no-max softmax, permlane
// P-exchange as r12 (the 62.4us version) -- but 64-key chunks: half the
// barriers/waits/loop iterations per key, 2x prefetch flight, two independent
// softmax chains per chunk (ILP). LDS 2x(8K+8K)=32KB.
// K buf [64 keys][64 dims], swizzle phys8 = log8 ^ (row&7).
// V buf [64 dims][64 keys], swizzle phys8 = (log8 + (row&7)) & 7.
static __device__ const int JQ[27] = {11, 0,0, 1,1, 2,2, 3,3, 4,4, 12, 5,5,
                                      6,6, 13, 7,7, 8,8, 14, 9,9, 15, 10,10};
static __device__ const int JK[27] = {0, 0,1, 0,1, 0,1, 0,1, 0,1, 0, 0,1,
                                      0,1, 0, 0,1, 0,1, 0, 0,1, 0, 0,1};

__global__ __launch_bounds__(256, 4) void attn_mfma(const short* __restrict__ q,
                                                    const short* __restrict__ k,
                                                    const short* __restrict__ vT,
                                                    short* __restrict__ ah,
                                                    float* __restrict__ yb,
                                                    float* __restrict__ side) {
  const int n = blockIdx.x;           // 864
  const int xcd = n & 7;
  const int t7 = n >> 3;              // 0..107
  const int bhj = t7 / 27;
  const int j = t7 - bhj * 27;
  const int bh = xcd * 4 + bhj;
  const int Q = JQ[j];
  const int kh = JK[j];
  const int split = (Q <= 10);
  const int q0 = Q * 128;

  const int tid = threadIdx.x;
  const int lane = tid & 63;
  const int wv = tid >> 6;
  const int l31 = lane & 31;
  const int hb = lane >> 5;
  const int qbase = q0 + wv * 32;
  const int tq = qbase + l31;

  const short* qgb = q + (size_t)bh * Tt * Dd;
  const short* kgb = k + (size_t)bh * Tt * Dd;
  const short* vgb = vT + (size_t)bh * Dd * Tt;

  // Q fragments: MFMA i covers dims 16i + 8hb..+7 (1/8*log2e folded)
  const short* qp = qgb + (size_t)tq * Dd + 8 * hb;
  half8v qf[4];
#pragma unroll
  for (int i = 0; i < 4; ++i) qf[i] = __builtin_bit_cast(half8v, *(const short8v*)(qp + 16 * i));

  __shared__ short Klds[2][4096];   // [buf][64 keys][64 dims], swizzled
  __shared__ short Vt[2][4096];     // [buf][64 dims][64 keys], swizzled

  // K staging: wave wv stages key rows 16wv..16wv+15 via 2 glls (8 rows each).
  // lane -> row +(lane>>3), phys chunk lane&7, src log chunk (lane&7)^(lane>>3)
  const int r8 = lane >> 3;
  const size_t ksrc0 = (size_t)(wv * 16 + r8) * Dd + (((lane & 7) ^ r8) << 3);
  const size_t ksrc1 = ksrc0 + (size_t)8 * Dd;
  // V staging: wave wv stages dim rows 16wv..16wv+15 via 2 glls.
  // phys chunk lane&7, src log chunk ((lane&7) - (lane>>3)) & 7
  const int vlog = ((lane & 7) - r8) & 7;
  const size_t vsrc0 = (size_t)(wv * 16 + r8) * Tt + (vlog << 3);
  const size_t vsrc1 = vsrc0 + (size_t)8 * Tt;

#define STAGE64(BUF, JT)                                                     \
  {                                                                          \
    gll16(kgb + (size_t)(JT) * Dd + ksrc0, &Klds[BUF][wv * 1024]);           \
    gll16(kgb + (size_t)(JT) * Dd + ksrc1, &Klds[BUF][wv * 1024 + 512]);     \
    gll16(vgb + vsrc0 + (JT), &Vt[BUF][wv * 1024]);                          \
    gll16(vgb + vsrc1 + (JT), &Vt[BUF][wv * 1024 + 512]);                    \
  }

  // K fragment read offsets (key row l31 / 32+l31; log chunk 2i+hb, phys = ^(l31&7))
  int koff[4], voff[4];
#pragma unroll
  for (int i = 0; i < 4; ++i) {
    koff[i] = l31 * 64 + (((2 * i + hb) ^ (l31 & 7)) << 3);
    voff[i] = l31 * 64 + ((((2 * i + hb) + (l31 & 7)) & 7) << 3);
  }

  f32x16 oacc[2];
#pragma unroll
  for (int t = 0; t < 2; ++t)
#pragma unroll
    for (int r = 0; r < 16; ++r) oacc[t][r] = 0.f;
  float lrun = 0.f;

  const int cs0 = (q0 >= 512) ? (q0 - 511) : 0;
  const int cstart = cs0 & ~63;
  const int nch_b = (Tt - cstart) >> 6;
  const int lower = (nch_b + 1) >> 1;
  const int mystart = cstart + ((split && kh) ? (lower << 6) : 0);
  const int myn = split ? (kh ? nch_b - lower : lower) : nch_b;

  // ---- prologue: stage chunk 0 ----
  STAGE64(0, mystart);
  __syncthreads();

  int cur = 0;
  for (int ci = 0; ci < myn; ++ci) {
    const int jt = mystart + (ci << 6);

    // prefetch next chunk into the other buffer (drains at end-of-chunk barrier)
    if (ci + 1 < myn) STAGE64(cur ^ 1, jt + 64);

    // ---- QK^T: two 32-key groups ----
    const short* kbuf = &Klds[cur][0];
    f32x16 seA, seB;
#pragma unroll
    for (int r = 0; r < 16; ++r) { seA[r] = 0.f; seB[r] = 0.f; }
    __builtin_amdgcn_s_setprio(1);
#pragma unroll
    for (int i = 0; i < 4; ++i) {
      half8v kfA = __builtin_bit_cast(half8v, *(short8v*)&kbuf[koff[i]]);
      seA = __builtin_amdgcn_mfma_f32_32x32x16_f16(kfA, qf[i], seA, 0, 0, 0);
    }
#pragma unroll
    for (int i = 0; i < 4; ++i) {
      half8v kfB = __builtin_bit_cast(half8v, *(short8v*)&kbuf[koff[i] + 2048]);
      seB = __builtin_amdgcn_mfma_f32_32x32x16_f16(kfB, qf[i], seB, 0, 0, 0);
    }
    __builtin_amdgcn_s_setprio(0);

    if (jt < qbase - 480) {   // boundary: window mask (keys jt+row / jt+32+row)
      int th = tq - 511 - jt;
#pragma unroll
      for (int r = 0; r < 16; ++r) {
        int row = (r & 3) + 8 * (r >> 2) + 4 * hb;
        if (row < th) seA[r] = -1e30f;
        if (32 + row < th) seB[r] = -1e30f;
      }
    }

    // ---- no-max softmax on both groups (independent chains -> ILP) ----
    float pA[16], pB[16];
    float psum = 0.f;
#pragma unroll
    for (int r = 0; r < 16; ++r) { pA[r] = exp2f(seA[r]); psum += pA[r]; }
#pragma unroll
    for (int r = 0; r < 16; ++r) { pB[r] = exp2f(seB[r]); psum += pB[r]; }
    psum += __shfl_xor(psum, 32);
    lrun += psum;

    // ---- pack to fp16 pairs; half-wave exchange via v_permlane32_swap ----
    unsigned pa[8], pb[8];
#pragma unroll
    for (int i = 0; i < 8; ++i) {
      pa[i] = __builtin_bit_cast(unsigned, __builtin_amdgcn_cvt_pkrtz(pA[2 * i], pA[2 * i + 1]));
      pb[i] = __builtin_bit_cast(unsigned, __builtin_amdgcn_cvt_pkrtz(pB[2 * i], pB[2 * i + 1]));
    }
    asm volatile("v_permlane32_swap_b32 %0, %1" : "+v"(pa[0]), "+v"(pa[2]));
    asm volatile("v_permlane32_swap_b32 %0, %1" : "+v"(pa[1]), "+v"(pa[3]));
    asm volatile("v_permlane32_swap_b32 %0, %1" : "+v"(pa[4]), "+v"(pa[6]));
    asm volatile("v_permlane32_swap_b32 %0, %1" : "+v"(pa[5]), "+v"(pa[7]));
    asm volatile("v_permlane32_swap_b32 %0, %1" : "+v"(pb[0]), "+v"(pb[2]));
    asm volatile("v_permlane32_swap_b32 %0, %1" : "+v"(pb[1]), "+v"(pb[3]));
    asm volatile("v_permlane32_swap_b32 %0, %1" : "+v"(pb[4]), "+v"(pb[6]));
    asm volatile("v_permlane32_swap_b32 %0, %1" : "+v"(pb[5]), "+v"(pb[7]));
    uint4v fA0, fA1, fB0, fB1;
    fA0[0] = pa[0]; fA0[1] = pa[1]; fA0[2] = pa[2]; fA0[3] = pa[3];
    fA1[0] = pa[4]; fA1[1] = pa[5]; fA1[2] = pa[6]; fA1[3] = pa[7];
    fB0[0] = pb[0]; fB0[1] = pb[1]; fB0[2] = pb[2]; fB0[3] = pb[3];
    fB1[0] = pb[4]; fB1[1] = pb[5]; fB1[2] = pb[6]; fB1[3] = pb[7];
    half8v pfA0 = __builtin_bit_cast(half8v, fA0);
    half8v pfA1 = __builtin_bit_cast(half8v, fA1);
    half8v pfB0 = __builtin_bit_cast(half8v, fB0);
    half8v pfB1 = __builtin_bit_cast(half8v, fB1);

    // ---- PV: key chunks i=0..3 <-> pfA0,pfA1,pfB0,pfB1 ----
    const short* vbuf = &Vt[cur][0];
    __builtin_amdgcn_s_setprio(1);
#pragma unroll
    for (int t = 0; t < 2; ++t) {
      const int ro = t * 2048;
      half8v v0 = __builtin_bit_cast(half8v, *(short8v*)&vbuf[voff[0] + ro]);
      half8v v1 = __builtin_bit_cast(half8v, *(short8v*)&vbuf[voff[1] + ro]);
      half8v v2 = __builtin_bit_cast(half8v, *(short8v*)&vbuf[voff[2] + ro]);
      half8v v3 = __builtin_bit_cast(half8v, *(short8v*)&vbuf[voff[3] + ro]);
      oacc[t] = __builtin_amdgcn_mfma_f32_32x32x16_f16(v0, pfA0, oacc[t], 0, 0, 0);
      oacc[t] = __builtin_amdgcn_mfma_f32_32x32x16_f16(v1, pfA1, oacc[t], 0, 0, 0);
      oacc[t] = __builtin_amdgcn_mfma_f32_32x32x16_f16(v2, pfB0, oacc[t], 0, 0, 0);
      oacc[t] = __builtin_amdgcn_mfma_f32_32x32x16_f16(v3, pfB1, oacc[t], 0, 0, 0);
    }
    __builtin_amdgcn_s_setprio(0);

    __syncthreads();
    cur ^= 1;
  }

  // ---- epilogue ----
  const float invl = 1.f / lrun;
  const int row = bh * Tt + tq;
  if (split && hb == 0) side[kh * 65536 + row] = lrun;
  const int bI = bh >> 4, hd = bh & 15;
  if (!split || kh == 0) {
    short* op = ah + ((size_t)(bI * Tt + tq)) * Cc + hd * Dd;
#pragma unroll
    for (int t = 0; t < 2; ++t)
#pragma unroll
      for (int rq = 0; rq < 4; ++rq) {
        short4v hv;
#pragma unroll
        for (int rr = 0; rr < 4; ++rr) hv[rr] = f2h(oacc[t][4 * rq + rr] * invl);
        *(short4v*)(op + 32 * t + 8 * rq + 4 * hb) = hv;
      }
  } else {
    float* yp = yb + (size_t)row * 64;
#pragma unroll
    for (int t = 0; t < 2; ++t)
#pragma unroll
      for (int rq = 0; rq < 4; ++rq) {
        f32x4 o4;
#pragma unroll
        for (int rr = 0; rr < 4; ++rr) o4[rr] = oacc[t][4 * rq + rr] * invl;
        *(f32x4*)(yp + 32 * t + 8 * rq + 4 * hb) = o4;
      }
  }
}

// ---------------- merge the two key-halves for split tiles (tq < 1408) ----------------
__global__ __launch_bounds__(256) void attn_merge(short* __restrict__ ah,
                                                  const float* __restrict__ yb,
                                                  const float* __restrict__ side) {
  const int bh = blockIdx.y;                         // 0..31
  const int idx = blockIdx.x * 256 + threadIdx.x;    // [0, 5632)
  const int tq = idx >> 2;                           // [0, 1408)
  const int qd = (idx & 3) << 4;
  const int row = bh * Tt + tq;
  const float l0 = side[row], l1 = side[65536 + row];
  const float inv = 1.f / (l0 + l1);
  const float a0 = l0 * inv, a1 = l1 * inv;

  const int bI = bh >> 4, hd = bh & 15;
  short* op = ah + ((size_t)(bI * Tt + tq)) * Cc + hd * Dd + qd;
  const float* yp = yb + (size_t)row * 64 + qd;

  short8v h0 = *(short8v*)op, h1 = *(short8v*)(op + 8);
  short8v o0, o1;
#pragma unroll
  for (int e = 0; e < 8; ++e) o0[e] = f2h(a0 * h2f(h0[e]) + a1 * yp[e]);
#pragma unroll
  for (int e = 0; e < 8; ++e) o1[e] = f2h(a0 * h2f(h1[e]) + a1 * yp[8 + e]);
  *(short8v*)op = o0;
  *(short8v*)(op + 8) = o1;
}

extern "C" void kernel_launch(void* const* d_in, const int* in_sizes, int n_in,
                              void* d_out, int out_size, void* d_ws, size_t ws_size,
                              hipStream_t stream) {
  const float* x  = (const float*)d_in[0];
  const float* Wq = (const float*)d_in[1];
  const float* bq = (const float*)d_in[2];
  const float* Wk = (const float*)d_in[3];
  const float* bk = (const float*)d_in[4];
  const float* Wv = (const float*)d_in[5];
  const float* bv = (const float*)d_in[6];
  const float* Wo = (const float*)d_in[7];
  const float* bo = (const float*)d_in[8];

  short* ws16 = (short*)d_ws;
  short* xh  = ws16;                  // 8MB fp16 x
  short* WTh = ws16 + 4194304;        // 8MB: Wq,Wk,Wv,Wo transposed fp16
  short* qb  = ws16 + 8388608;        // 8MB fp16 [B,H,T,D]
  short* kb  = ws16 + 12582912;       // 8MB fp16 [B,H,T,D]
  short* vb  = ws16 + 16777216;       // 8MB fp16 [B,H,D,T] (V transposed)
  short* ah  = ws16 + 20971520;       // 8MB fp16 attn out [B,T,C]
  float* yb   = (float*)(ws16 + 25165824);  // 16.78MB fp32 kh=1 partials [65536][64]
  float* side = yb + 4194304;               // 0.5MB: [kh][65536] = l

  cast_x<<<2048, 256, 0, stream>>>(x, xh);
  cast_wT<<<dim3(16, 16, 4), 256, 0, stream>>>(Wq, Wk, Wv, Wo, WTh);

  gemm_qkv<<<dim3(256, 3), 256, 0, stream>>>(xh, WTh, bq, bk, bv, qb, kb, vb);

  attn_mfma<<<864, 256, 0, stream>>>(qb, kb, vb, ah, yb, side);
  attn_merge<<<dim3(22, 32), 256, 0, stream>>>(ah, yb, side);

  gemm_out<<<256, 256, 0, stream>>>(ah, WTh + 3 * 1048576, bo, (float*)d_out);
}

// Round 16
// 118.936 us; speedup vs baseline: 1.2935x; 1.1283x over previous
//
#include <hip/hip_runtime.h>
#include <hip/hip_bf16.h>
#include <math.h>

#define Bsz 2
#define Tt  2048
#define Cc  1024
#define Hh  16
#define Dd  64

typedef __attribute__((ext_vector_type(8))) short short8v;
typedef __attribute__((ext_vector_type(4))) short short4v;
typedef __attribute__((ext_vector_type(8))) _Float16 half8v;
typedef __attribute__((ext_vector_type(4))) float f32x4;
typedef __attribute__((ext_vector_type(16))) float f32x16;
typedef __attribute__((ext_vector_type(4))) unsigned int uint4v;

static __device__ __forceinline__ short f2h(float f) {
  _Float16 h = (_Float16)f;   // v_cvt_f16_f32 (RNE)
  return __builtin_bit_cast(short, h);
}
static __device__ __forceinline__ float h2f(short s) {
  _Float16 h = __builtin_bit_cast(_Float16, s);
  return (float)h;
}
static __device__ __forceinline__ void gll16(const void* g, void* l) {
  __builtin_amdgcn_global_load_lds((const __attribute__((address_space(1))) unsigned int*)g,
                                   (__attribute__((address_space(3))) unsigned int*)l, 16, 0, 0);
}

// ---------------- prepass: cast x to fp16 ----------------
__global__ void cast_x(const float* __restrict__ x, short* __restrict__ xh) {
  int t = blockIdx.x * 256 + threadIdx.x;
  const float* s = x + (size_t)t * 8;
  float4 a = *(const float4*)s, b = *(const float4*)(s + 4);
  short8v h;
  h[0] = f2h(a.x); h[1] = f2h(a.y); h[2] = f2h(a.z); h[3] = f2h(a.w);
  h[4] = f2h(b.x); h[5] = f2h(b.y); h[6] = f2h(b.z); h[7] = f2h(b.w);
  *(short8v*)(xh + (size_t)t * 8) = h;
}

// ---------------- prepass: cast + transpose W -> Wt[n][k] fp16 ----------------
__global__ __launch_bounds__(256) void cast_wT(const float* __restrict__ Wq,
                                               const float* __restrict__ Wk,
                                               const float* __restrict__ Wv,
                                               const float* __restrict__ Wo,
                                               short* __restrict__ WTh) {
  __shared__ float T[64][68];
  const int z = blockIdx.z;
  const float* W = z == 0 ? Wq : z == 1 ? Wk : z == 2 ? Wv : Wo;
  short* oh = WTh + (size_t)z * 1048576;
  const int n0 = blockIdx.x * 64, k0 = blockIdx.y * 64;
  const int tid = threadIdx.x;
#pragma unroll
  for (int i = 0; i < 4; ++i) {
    int slot = tid + i * 256;
    int r = slot >> 4, c4 = (slot & 15) << 2;
    *(float4*)&T[r][c4] = *(const float4*)(W + (size_t)(k0 + r) * Cc + n0 + c4);
  }
  __syncthreads();
#pragma unroll
  for (int i = 0; i < 2; ++i) {
    int slot = tid + i * 256;
    int nl = slot >> 3, ks = (slot & 7) << 3;
    short8v h;
#pragma unroll
    for (int e = 0; e < 8; ++e) h[e] = f2h(T[ks + e][nl]);
    *(short8v*)(oh + (size_t)(n0 + nl) * Cc + k0 + ks) = h;
  }
}

// ================= 128x128 fp16 GEMM core, BK=64 =================
// Per K-step: 8 gll (4 A + 4 B per wave covers its 32 rows) + 2 barriers +
// 2 sub-steps of {8 ds_read_b128, 16 MFMA} -> 32 MFMA per barrier pair
// (2x the BK=32 core). LDS [128][64] per operand, swizzle phys8 = log8^(row&7),
// staged with pre-swizzled gll source (both-sides rule).
__device__ __forceinline__ void core128h(const short* __restrict__ Ah,
                                         const short* __restrict__ Bh,
                                         short* AhL, short* BhL,
                                         int row0, int col0, int wv, int lane, f32x4 acc[4][4]) {
  const int l15 = lane & 15, g = lane >> 4;
  const int wr = wv >> 1, wc = wv & 1;

  const int r8 = lane >> 3;                       // row-in-gll 0..7
  const int sch = ((lane & 7) ^ r8) << 3;         // source log chunk (shorts)
  size_t aoff[4], boff[4];
#pragma unroll
  for (int gi = 0; gi < 4; ++gi) {
    aoff[gi] = (size_t)(row0 + wv * 32 + 8 * gi + r8) * Cc + sch;
    boff[gi] = (size_t)(col0 + wv * 32 + 8 * gi + r8) * Cc + sch;
  }
  short* dA = AhL + wv * 2048;
  short* dB = BhL + wv * 2048;

  int aL[4][2], bL[4][2];
#pragma unroll
  for (int m = 0; m < 4; ++m)
#pragma unroll
    for (int s = 0; s < 2; ++s) {
      aL[m][s] = (wr * 64 + m * 16 + l15) * 64 + (((4 * s + g) ^ (l15 & 7)) << 3);
      bL[m][s] = (wc * 64 + m * 16 + l15) * 64 + (((4 * s + g) ^ (l15 & 7)) << 3);
    }

  for (int k0 = 0; k0 < Cc; k0 += 64) {
    __syncthreads();
#pragma unroll
    for (int gi = 0; gi < 4; ++gi) {
      gll16(Ah + aoff[gi] + k0, dA + gi * 512);
      gll16(Bh + boff[gi] + k0, dB + gi * 512);
    }
    __syncthreads();
#pragma unroll
    for (int s = 0; s < 2; ++s) {
      half8v a[4], b[4];
#pragma unroll
      for (int m = 0; m < 4; ++m) a[m] = __builtin_bit_cast(half8v, *(short8v*)&AhL[aL[m][s]]);
#pragma unroll
      for (int n = 0; n < 4; ++n) b[n] = __builtin_bit_cast(half8v, *(short8v*)&BhL[bL[n][s]]);
#pragma unroll
      for (int m = 0; m < 4; ++m)
#pragma unroll
        for (int n = 0; n < 4; ++n)
          acc[m][n] = __builtin_amdgcn_mfma_f32_16x16x32_f16(a[m], b[n], acc[m][n], 0, 0, 0);
    }
  }
}

// ---------------- QKV projection GEMM (fp16), rope fused, V transposed ----------------
__global__ __launch_bounds__(256, 3) void gemm_qkv(const short* __restrict__ xh,
                                                   const short* __restrict__ WTh,
                                                   const float* __restrict__ bq,
                                                   const float* __restrict__ bk,
                                                   const float* __restrict__ bv,
                                                   short* __restrict__ qb,
                                                   short* __restrict__ kb,
                                                   short* __restrict__ vb) {
  __shared__ short AhL[8192], BhL[8192];
  const int mode = blockIdx.y;
  const short* Bh = WTh + (size_t)mode * 1048576;
  const float* bias = mode == 0 ? bq : mode == 1 ? bk : bv;
  short* Y = mode == 0 ? qb : mode == 1 ? kb : vb;

  const int bid = blockIdx.x;
  const int nid = ((bid & 7) << 5) | (bid >> 3);
  const int row0 = (nid >> 3) * 128, col0 = (nid & 7) * 128;
  const int lane = threadIdx.x & 63, wv = threadIdx.x >> 6;
  const int l15 = lane & 15, g = lane >> 4;
  const int wr = wv >> 1, wc = wv & 1;

  f32x4 acc[4][4];
#pragma unroll
  for (int m = 0; m < 4; ++m)
#pragma unroll
    for (int n = 0; n < 4; ++n) acc[m][n] = (f32x4){0.f, 0.f, 0.f, 0.f};

  core128h(xh, Bh, AhL, BhL, row0, col0, wv, lane, acc);

  const int cbase = col0 + wc * 64;
  const int h = cbase >> 6;
  if (mode < 2) {
    const float scale = (mode == 0) ? 0.18033688f : 1.0f;   // 1/8 * log2(e) folded for Q
#pragma unroll
    for (int n = 0; n < 2; ++n) {
      const int d = n * 16 + l15;
      const float b0 = bias[cbase + d], b1 = bias[cbase + d + 32];
      const float inv = exp2f(-(float)d * (13.2877123795494f / 32.f));
#pragma unroll
      for (int m = 0; m < 4; ++m)
#pragma unroll
        for (int rr = 0; rr < 4; ++rr) {
          int R = row0 + wr * 64 + m * 16 + g * 4 + rr;
          int bI = R >> 11, t = R & (Tt - 1);
          float sn, cs;
          sincosf((float)t * inv, &sn, &cs);
          float v0 = acc[m][n][rr] + b0, v1 = acc[m][n + 2][rr] + b1;
          size_t base = (((size_t)(bI * Hh + h) * Tt + t) << 6) + d;
          Y[base]      = f2h((v0 * cs - v1 * sn) * scale);
          Y[base + 32] = f2h((v1 * cs + v0 * sn) * scale);
        }
    }
  } else {
    // V: write transposed [B,H,D,T] fp16
#pragma unroll
    for (int n = 0; n < 2; ++n) {
      const int d = n * 16 + l15;
      const float b0 = bias[cbase + d], b1 = bias[cbase + d + 32];
#pragma unroll
      for (int m = 0; m < 4; ++m) {
        int R = row0 + wr * 64 + m * 16 + g * 4;
        int bI = R >> 11, t = R & (Tt - 1);
        short4v s0, s1;
#pragma unroll
        for (int rr = 0; rr < 4; ++rr) {
          s0[rr] = f2h(acc[m][n][rr] + b0);
          s1[rr] = f2h(acc[m][n + 2][rr] + b1);
        }
        size_t base = ((size_t)(bI * Hh + h) * Dd);
        *(short4v*)(Y + (base + d) * Tt + t)      = s0;
        *(short4v*)(Y + (base + d + 32) * Tt + t) = s1;
      }
    }
  }
}

// ---------------- final output GEMM (fp16 core, fp32 out) ----------------
__global__ __launch_bounds__(256, 3) void gemm_out(const short* __restrict__ ah,
                                                   const short* __restrict__ WTo,
                                                   const float* __restrict__ bias,
                                                   float* __restrict__ Y) {
  __shared__ short AhL[8192], BhL[8192];
  const int bid = blockIdx.x;
  const int nid = ((bid & 7) << 5) | (bid >> 3);
  const int row0 = (nid >> 3) * 128, col0 = (nid & 7) * 128;
  const int lane = threadIdx.x & 63, wv = threadIdx.x >> 6;
  const int l15 = lane & 15, g = lane >> 4;
  const int wr = wv >> 1, wc = wv & 1;

  f32x4 acc[4][4];
#pragma unroll
  for (int m = 0; m < 4; ++m)
#pragma unroll
    for (int n = 0; n < 4; ++n) acc[m][n] = (f32x4){0.f, 0.f, 0.f, 0.f};

  core128h(ah, WTo, AhL, BhL, row0, col0, wv, lane, acc);

  const int cbase = col0 + wc * 64;
#pragma unroll
  for (int n = 0; n < 2; ++n) {
    const int ccol = cbase + n * 16 + l15;
    const float b0 = bias[ccol], b1 = bias[ccol + 32];
#pragma unroll
    for (int m = 0; m < 4; ++m)
#pragma unroll
      for (int rr = 0; rr < 4; ++rr) {
        int R = row0 + wr * 64 + m * 16 + g * 4 + rr;
        Y[(size_t)R * Cc + ccol]      = acc[m][n][rr] + b0;
        Y[(size_t)R * Cc + ccol + 32] = acc[m][n + 2][rr] + b1;
      }
  }
}

// ================= MFMA flash attention (r15 structure, KVBLK=64) =============
// Changes vs r15: exp via bare inline-asm v_exp_f32 (avoids any OCML fixup
// code), psum as 4 independent chains (cuts 32-deep serial fp-add chain).
static __device__ const int JQ[27] = {11, 0,0, 1,1, 2,2, 3,3, 4,4, 12, 5,5,
                                      6,6, 13, 7,7, 8,8, 14, 9,9, 15, 10,10};
static __device__ const int JK[27] = {0, 0,1, 0,1, 0,1, 0,1, 0,1, 0, 0,1,
                                      0,1, 0, 0,1, 0,1, 0, 0,1, 0, 0,1};

__global__ __launch_bounds__(256, 4) void attn_mfma(const short* __restrict__ q,
                                                    const short* __restrict__ k,
                                                    const short* __restrict__ vT,
                                                    short* __restrict__ ah,
                                                    float* __restrict__ yb,
                                                    float* __restrict__ side) {
  const int n = blockIdx.x;           // 864
  const int xcd = n & 7;
  const int t7 = n >> 3;              // 0..107
  const int bhj = t7 / 27;
  const int j = t7 - bhj * 27;
  const int bh = xcd * 4 + bhj;
  const int Q = JQ[j];
  const int kh = JK[j];
  const int split = (Q <= 10);
  const int q0 = Q * 128;

  const int tid = threadIdx.x;
  const int lane = tid & 63;
  const int wv = tid >> 6;
  const int l31 = lane & 31;
  const int hb = lane >> 5;
  const int qbase = q0 + wv * 32;
  const int tq = qbase + l31;

  const short* qgb = q + (size_t)bh * Tt * Dd;
  const short* kgb = k + (size_t)bh * Tt * Dd;
  const short* vgb = vT + (size_t)bh * Dd * Tt;

  // Q fragments: MFMA i covers dims 16i + 8hb..+7 (1/8*log2e folded)
  const short* qp = qgb + (size_t)tq * Dd + 8 * hb;
  half8v qf[4];
#pragma unroll
  for (int i = 0; i < 4; ++i) qf[i] = __builtin_bit_cast(half8v, *(const short8v*)(qp + 16 * i));

  __shared__ short Klds[2][4096];   // [buf][64 keys][64 dims], swizzled
  __shared__ short Vt[2][4096];     // [buf][64 dims][64 keys], swizzled

  // K staging: wave wv stages key rows 16wv..16wv+15 via 2 glls (8 rows each).
  const int r8 = lane >> 3;
  const size_t ksrc0 = (size_t)(wv * 16 + r8) * Dd + (((lane & 7) ^ r8) << 3);
  const size_t ksrc1 = ksrc0 + (size_t)8 * Dd;
  // V staging: wave wv stages dim rows 16wv..16wv+15 via 2 glls.
  const int vlog = ((lane & 7) - r8) & 7;
  const size_t vsrc0 = (size_t)(wv * 16 + r8) * Tt + (vlog << 3);
  const size_t vsrc1 = vsrc0 + (size_t)8 * Tt;

#define STAGE64(BUF, JT)                                                     \
  {                                                                          \
    gll16(kgb + (size_t)(JT) * Dd + ksrc0, &Klds[BUF][wv * 1024]);           \
    gll16(kgb + (size_t)(JT) * Dd + ksrc1, &Klds[BUF][wv * 1024 + 512]);     \
    gll16(vgb + vsrc0 + (JT), &Vt[BUF][wv * 1024]);                          \
    gll16(vgb + vsrc1 + (JT), &Vt[BUF][wv * 1024 + 512]);                    \
  }

  int koff[4], voff[4];
#pragma unroll
  for (int i = 0; i < 4; ++i) {
    koff[i] = l31 * 64 + (((2 * i + hb) ^ (l31 & 7)) << 3);
    voff[i] = l31 * 64 + ((((2 * i + hb) + (l31 & 7)) & 7) << 3);
  }

  f32x16 oacc[2];
#pragma unroll
  for (int t = 0; t < 2; ++t)
#pragma unroll
    for (int r = 0; r < 16; ++r) oacc[t][r] = 0.f;
  float lrun = 0.f;

  const int cs0 = (q0 >= 512) ? (q0 - 511) : 0;
  const int cstart = cs0 & ~63;
  const int nch_b = (Tt - cstart) >> 6;
  const int lower = (nch_b + 1) >> 1;
  const int mystart = cstart + ((split && kh) ? (lower << 6) : 0);
  const int myn = split ? (kh ? nch_b - lower : lower) : nch_b;

  // ---- prologue: stage chunk 0 ----
  STAGE64(0, mystart);
  __syncthreads();

  int cur = 0;
  for (int ci = 0; ci < myn; ++ci) {
    const int jt = mystart + (ci << 6);

    if (ci + 1 < myn) STAGE64(cur ^ 1, jt + 64);

    // ---- QK^T: two 32-key groups ----
    const short* kbuf = &Klds[cur][0];
    f32x16 seA, seB;
#pragma unroll
    for (int r = 0; r < 16; ++r) { seA[r] = 0.f; seB[r] = 0.f; }
    __builtin_amdgcn_s_setprio(1);
#pragma unroll
    for (int i = 0; i < 4; ++i) {
      half8v kfA = __builtin_bit_cast(half8v, *(short8v*)&kbuf[koff[i]]);
      seA = __builtin_amdgcn_mfma_f32_32x32x16_f16(kfA, qf[i], seA, 0, 0, 0);
    }
#pragma unroll
    for (int i = 0; i < 4; ++i) {
      half8v kfB = __builtin_bit_cast(half8v, *(short8v*)&kbuf[koff[i] + 2048]);
      seB = __builtin_amdgcn_mfma_f32_32x32x16_f16(kfB, qf[i], seB, 0, 0, 0);
    }
    __builtin_amdgcn_s_setprio(0);

    if (jt < qbase - 480) {   // boundary: window mask
      int th = tq - 511 - jt;
#pragma unroll
      for (int r = 0; r < 16; ++r) {
        int row = (r & 3) + 8 * (r >> 2) + 4 * hb;
        if (row < th) seA[r] = -1e30f;
        if (32 + row < th) seB[r] = -1e30f;
      }
    }

    // ---- no-max softmax: p = exp2(se) via bare v_exp_f32 ----
    float pA[16], pB[16];
#pragma unroll
    for (int r = 0; r < 16; ++r) {
      asm("v_exp_f32 %0, %1" : "=v"(pA[r]) : "v"(seA[r]));
      asm("v_exp_f32 %0, %1" : "=v"(pB[r]) : "v"(seB[r]));
    }
    float t0 = 0.f, t1 = 0.f, t2 = 0.f, t3 = 0.f;
#pragma unroll
    for (int r = 0; r < 16; r += 4) {
      t0 += pA[r];     t1 += pA[r + 1]; t2 += pA[r + 2]; t3 += pA[r + 3];
      t0 += pB[r];     t1 += pB[r + 1]; t2 += pB[r + 2]; t3 += pB[r + 3];
    }
    float psum = (t0 + t1) + (t2 + t3);
    psum += __shfl_xor(psum, 32);
    lrun += psum;

    // ---- pack to fp16 pairs; half-wave exchange via v_permlane32_swap ----
    unsigned pa[8], pb[8];
#pragma unroll
    for (int i = 0; i < 8; ++i) {
      pa[i] = __builtin_bit_cast(unsigned, __builtin_amdgcn_cvt_pkrtz(pA[2 * i], pA[2 * i + 1]));
      pb[i] = __builtin_bit_cast(unsigned, __builtin_amdgcn_cvt_pkrtz(pB[2 * i], pB[2 * i + 1]));
    }
    asm volatile("v_permlane32_swap_b32 %0, %1" : "+v"(pa[0]), "+v"(pa[2]));
    asm volatile("v_permlane32_swap_b32 %0, %1" : "+v"(pa[1]), "+v"(pa[3]));
    asm volatile("v_permlane32_swap_b32 %0, %1" : "+v"(pa[4]), "+v"(pa[6]));
    asm volatile("v_permlane32_swap_b32 %0, %1" : "+v"(pa[5]), "+v"(pa[7]));
    asm volatile("v_permlane32_swap_b32 %0, %1" : "+v"(pb[0]), "+v"(pb[2]));
    asm volatile("v_permlane32_swap_b32 %0, %1" : "+v"(pb[1]), "+v"(pb[3]));
    asm volatile("v_permlane32_swap_b32 %0, %1" : "+v"(pb[4]), "+v"(pb[6]));
    asm volatile("v_permlane32_swap_b32 %0, %1" : "+v"(pb[5]), "+v"(pb[7]));
    uint4v fA0, fA1, fB0, fB1;
    fA0[0] = pa[0]; fA0[1] = pa[1]; fA0[2] = pa[2]; fA0[3] = pa[3];
    fA1[0] = pa[4]; fA1[1] = pa[5]; fA1[2] = pa[6]; fA1[3] = pa[7];
    fB0[0] = pb[0]; fB0[1] = pb[1]; fB0[2] = pb[2]; fB0[3] = pb[3];
    fB1[0] = pb[4]; fB1[1] = pb[5]; fB1[2] = pb[6]; fB1[3] = pb[7];
    half8v pfA0 = __builtin_bit_cast(half8v, fA0);
    half8v pfA1 = __builtin_bit_cast(half8v, fA1);
    half8v pfB0 = __builtin_bit_cast(half8v, fB0);
    half8v pfB1 = __builtin_bit_cast(half8v, fB1);

    // ---- PV ----
    const short* vbuf = &Vt[cur][0];
    __builtin_amdgcn_s_setprio(1);
#pragma unroll
    for (int t = 0; t < 2; ++t) {
      const int ro = t * 2048;
      half8v v0 = __builtin_bit_cast(half8v, *(short8v*)&vbuf[voff[0] + ro]);
      half8v v1 = __builtin_bit_cast(half8v, *(short8v*)&vbuf[voff[1] + ro]);
      half8v v2 = __builtin_bit_cast(half8v, *(short8v*)&vbuf[voff[2] + ro]);
      half8v v3 = __builtin_bit_cast(half8v, *(short8v*)&vbuf[voff[3] + ro]);
      oacc[t] = __builtin_amdgcn_mfma_f32_32x32x16_f16(v0, pfA0, oacc[t], 0, 0, 0);
      oacc[t] = __builtin_amdgcn_mfma_f32_32x32x16_f16(v1, pfA1, oacc[t], 0, 0, 0);
      oacc[t] = __builtin_amdgcn_mfma_f32_32x32x16_f16(v2, pfB0, oacc[t], 0, 0, 0);
      oacc[t] = __builtin_amdgcn_mfma_f32_32x32x16_f16(v3, pfB1, oacc[t], 0, 0, 0);
    }
    __builtin_amdgcn_s_setprio(0);

    __syncthreads();
    cur ^= 1;
  }

  // ---- epilogue ----
  const float invl = 1.f / lrun;
  const int row = bh * Tt + tq;
  if (split && hb == 0) side[kh * 65536 + row] = lrun;
  const int bI = bh >> 4, hd = bh & 15;
  if (!split || kh == 0) {
    short* op = ah + ((size_t)(bI * Tt + tq)) * Cc + hd * Dd;
#pragma unroll
    for (int t = 0; t < 2; ++t)
#pragma unroll
      for (int rq = 0; rq < 4; ++rq) {
        short4v hv;
#pragma unroll
        for (int rr = 0; rr < 4; ++rr) hv[rr] = f2h(oacc[t][4 * rq + rr] * invl);
        *(short4v*)(op + 32 * t + 8 * rq + 4 * hb) = hv;
      }
  } else {
    float* yp = yb + (size_t)row * 64;
#pragma unroll
    for (int t = 0; t < 2; ++t)
#pragma unroll
      for (int rq = 0; rq < 4; ++rq) {
        f32x4 o4;
#pragma unroll
        for (int rr = 0; rr < 4; ++rr) o4[rr] = oacc[t][4 * rq + rr] * invl;
        *(f32x4*)(yp + 32 * t + 8 * rq + 4 * hb) = o4;
      }
  }
}

// ---------------- merge the two key-halves for split tiles (tq < 1408) ----------------
__global__ __launch_bounds__(256) void attn_merge(short* __restrict__ ah,
                                                  const float* __restrict__ yb,
                                                  const float* __restrict__ side) {
  const int bh = blockIdx.y;                         // 0..31
  const int idx = blockIdx.x * 256 + threadIdx.x;    // [0, 5632)
  const int tq = idx >> 2;                           // [0, 1408)
  const int qd = (idx & 3) << 4;
  const int row = bh * Tt + tq;
  const float l0 = side[row], l1 = side[65536 + row];
  const float inv = 1.f / (l0 + l1);
  const float a0 = l0 * inv, a1 = l1 * inv;

  const int bI = bh >> 4, hd = bh & 15;
  short* op = ah + ((size_t)(bI * Tt + tq)) * Cc + hd * Dd + qd;
  const float* yp = yb + (size_t)row * 64 + qd;

  short8v h0 = *(short8v*)op, h1 = *(short8v*)(op + 8);
  short8v o0, o1;
#pragma unroll
  for (int e = 0; e < 8; ++e) o0[e] = f2h(a0 * h2f(h0[e]) + a1 * yp[e]);
#pragma unroll
  for (int e = 0; e < 8; ++e) o1[e] = f2h(a0 * h2f(h1[e]) + a1 * yp[8 + e]);
  *(short8v*)op = o0;
  *(short8v*)(op + 8) = o1;
}

extern "C" void kernel_launch(void* const* d_in, const int* in_sizes, int n_in,
                              void* d_out, int out_size, void* d_ws, size_t ws_size,
                              hipStream_t stream) {
  const float* x  = (const float*)d_in[0];
  const float* Wq = (const float*)d_in[1];
  const float* bq = (const float*)d_in[2];
  const float* Wk = (const float*)d_in[3];
  const float* bk = (const float*)d_in[4];
  const float* Wv = (const float*)d_in[5];
  const float* bv = (const float*)d_in[6];
  const float* Wo = (const float*)d_in[7];
  const float* bo = (const float*)d_in[8];

  short* ws16 = (short*)d_ws;
  short* xh  = ws16;                  // 8MB fp16 x
  short* WTh = ws16 + 4194304;        // 8MB: Wq,Wk,Wv,Wo transposed fp16
  short* qb  = ws16 + 8388608;        // 8MB fp16 [B,H,T,D]
  short* kb  = ws16 + 12582912;       // 8MB fp16 [B,H,T,D]
  short* vb  = ws16 + 16777216;       // 8MB fp16 [B,H,D,T] (V transposed)
  short* ah  = ws16 + 20971520;       // 8MB fp16 attn out [B,T,C]
  float* yb   = (float*)(ws16 + 25165824);  // 16.78MB fp32 kh=1 partials [65536][64]
  float* side = yb + 4194304;               // 0.5MB: [kh][65536] = l

  cast_x<<<2048, 256, 0, stream>>>(x, xh);
  cast_wT<<<dim3(16, 16, 4), 256, 0, stream>>>(Wq, Wk, Wv, Wo, WTh);

  gemm_qkv<<<dim3(256, 3), 256, 0, stream>>>(xh, WTh, bq, bk, bv, qb, kb, vb);

  attn_mfma<<<864, 256, 0, stream>>>(qb, kb, vb, ah, yb, side);
  attn_merge<<<dim3(22, 32), 256, 0, stream>>>(ah, yb, side);

  gemm_out<<<256, 256, 0, stream>>>(ah, WTh + 3 * 1048576, bo, (float*)d_out);
}

// Round 17
// 117.883 us; speedup vs baseline: 1.3051x; 1.0089x over previous
//
#include <hip/hip_runtime.h>
#include <hip/hip_bf16.h>
#include <math.h>

#define Bsz 2
#define Tt  2048
#define Cc  1024
#define Hh  16
#define Dd  64

typedef __attribute__((ext_vector_type(8))) short short8v;
typedef __attribute__((ext_vector_type(4))) short short4v;
typedef __attribute__((ext_vector_type(8))) _Float16 half8v;
typedef __attribute__((ext_vector_type(4))) float f32x4;
typedef __attribute__((ext_vector_type(16))) float f32x16;
typedef __attribute__((ext_vector_type(4))) unsigned int uint4v;

static __device__ __forceinline__ short f2h(float f) {
  _Float16 h = (_Float16)f;   // v_cvt_f16_f32 (RNE)
  return __builtin_bit_cast(short, h);
}
static __device__ __forceinline__ float h2f(short s) {
  _Float16 h = __builtin_bit_cast(_Float16, s);
  return (float)h;
}
static __device__ __forceinline__ void gll16(const void* g, void* l) {
  __builtin_amdgcn_global_load_lds((const __attribute__((address_space(1))) unsigned int*)g,
                                   (__attribute__((address_space(3))) unsigned int*)l, 16, 0, 0);
}

// ---------------- fused prepass: cast x, cast+transpose W, rope table ----------------
// blocks [0,2048): x -> fp16.  [2048,3072): W -> Wt[n][k] fp16 (4 x 256 tiles).
// [3072,3328): rope table rt[t][p] = (cos, sin)(t * 10000^(-p/32)).
__global__ __launch_bounds__(256) void prep(const float* __restrict__ x,
                                            const float* __restrict__ Wq,
                                            const float* __restrict__ Wk,
                                            const float* __restrict__ Wv,
                                            const float* __restrict__ Wo,
                                            short* __restrict__ xh,
                                            short* __restrict__ WTh,
                                            float* __restrict__ rt) {
  __shared__ float T[64][68];
  const int bid = blockIdx.x;
  const int tid = threadIdx.x;

  if (bid < 2048) {           // ---- cast x ----
    int t = bid * 256 + tid;
    const float* s = x + (size_t)t * 8;
    float4 a = *(const float4*)s, b = *(const float4*)(s + 4);
    short8v h;
    h[0] = f2h(a.x); h[1] = f2h(a.y); h[2] = f2h(a.z); h[3] = f2h(a.w);
    h[4] = f2h(b.x); h[5] = f2h(b.y); h[6] = f2h(b.z); h[7] = f2h(b.w);
    *(short8v*)(xh + (size_t)t * 8) = h;
  } else if (bid < 3072) {    // ---- cast + transpose W ----
    const int z = (bid - 2048) >> 8;
    const int slot = (bid - 2048) & 255;
    const float* W = z == 0 ? Wq : z == 1 ? Wk : z == 2 ? Wv : Wo;
    short* oh = WTh + (size_t)z * 1048576;
    const int n0 = (slot & 15) * 64, k0 = (slot >> 4) * 64;
#pragma unroll
    for (int i = 0; i < 4; ++i) {
      int s2 = tid + i * 256;
      int r = s2 >> 4, c4 = (s2 & 15) << 2;
      *(float4*)&T[r][c4] = *(const float4*)(W + (size_t)(k0 + r) * Cc + n0 + c4);
    }
    __syncthreads();
#pragma unroll
    for (int i = 0; i < 2; ++i) {
      int s2 = tid + i * 256;
      int nl = s2 >> 3, ks = (s2 & 7) << 3;
      short8v h;
#pragma unroll
      for (int e = 0; e < 8; ++e) h[e] = f2h(T[ks + e][nl]);
      *(short8v*)(oh + (size_t)(n0 + nl) * Cc + k0 + ks) = h;
    }
  } else {                    // ---- rope table ----
    int idx = (bid - 3072) * 256 + tid;   // [0, 65536)
    int t = idx >> 5, p = idx & 31;
    float inv = exp2f(-(float)p * (13.2877123795494f / 32.f));
    float sn, cs;
    sincosf((float)t * inv, &sn, &cs);
    float2 v; v.x = cs; v.y = sn;
    *(float2*)(rt + (size_t)idx * 2) = v;
  }
}

// ================= 128x128 fp16 GEMM core, BK=64 =================
__device__ __forceinline__ void core128h(const short* __restrict__ Ah,
                                         const short* __restrict__ Bh,
                                         short* AhL, short* BhL,
                                         int row0, int col0, int wv, int lane, f32x4 acc[4][4]) {
  const int l15 = lane & 15, g = lane >> 4;
  const int wr = wv >> 1, wc = wv & 1;

  const int r8 = lane >> 3;                       // row-in-gll 0..7
  const int sch = ((lane & 7) ^ r8) << 3;         // source log chunk (shorts)
  size_t aoff[4], boff[4];
#pragma unroll
  for (int gi = 0; gi < 4; ++gi) {
    aoff[gi] = (size_t)(row0 + wv * 32 + 8 * gi + r8) * Cc + sch;
    boff[gi] = (size_t)(col0 + wv * 32 + 8 * gi + r8) * Cc + sch;
  }
  short* dA = AhL + wv * 2048;
  short* dB = BhL + wv * 2048;

  int aL[4][2], bL[4][2];
#pragma unroll
  for (int m = 0; m < 4; ++m)
#pragma unroll
    for (int s = 0; s < 2; ++s) {
      aL[m][s] = (wr * 64 + m * 16 + l15) * 64 + (((4 * s + g) ^ (l15 & 7)) << 3);
      bL[m][s] = (wc * 64 + m * 16 + l15) * 64 + (((4 * s + g) ^ (l15 & 7)) << 3);
    }

  for (int k0 = 0; k0 < Cc; k0 += 64) {
    __syncthreads();
#pragma unroll
    for (int gi = 0; gi < 4; ++gi) {
      gll16(Ah + aoff[gi] + k0, dA + gi * 512);
      gll16(Bh + boff[gi] + k0, dB + gi * 512);
    }
    __syncthreads();
#pragma unroll
    for (int s = 0; s < 2; ++s) {
      half8v a[4], b[4];
#pragma unroll
      for (int m = 0; m < 4; ++m) a[m] = __builtin_bit_cast(half8v, *(short8v*)&AhL[aL[m][s]]);
#pragma unroll
      for (int n = 0; n < 4; ++n) b[n] = __builtin_bit_cast(half8v, *(short8v*)&BhL[bL[n][s]]);
#pragma unroll
      for (int m = 0; m < 4; ++m)
#pragma unroll
        for (int n = 0; n < 4; ++n)
          acc[m][n] = __builtin_amdgcn_mfma_f32_16x16x32_f16(a[m], b[n], acc[m][n], 0, 0, 0);
    }
  }
}

// ---------------- QKV projection GEMM (fp16), rope via table, V transposed ----------------
__global__ __launch_bounds__(256, 3) void gemm_qkv(const short* __restrict__ xh,
                                                   const short* __restrict__ WTh,
                                                   const float* __restrict__ bq,
                                                   const float* __restrict__ bk,
                                                   const float* __restrict__ bv,
                                                   const float* __restrict__ rt,
                                                   short* __restrict__ qb,
                                                   short* __restrict__ kb,
                                                   short* __restrict__ vb) {
  __shared__ short AhL[8192], BhL[8192];
  const int mode = blockIdx.y;
  const short* Bh = WTh + (size_t)mode * 1048576;
  const float* bias = mode == 0 ? bq : mode == 1 ? bk : bv;
  short* Y = mode == 0 ? qb : mode == 1 ? kb : vb;

  const int bid = blockIdx.x;
  const int nid = ((bid & 7) << 5) | (bid >> 3);
  const int row0 = (nid >> 3) * 128, col0 = (nid & 7) * 128;
  const int lane = threadIdx.x & 63, wv = threadIdx.x >> 6;
  const int l15 = lane & 15, g = lane >> 4;
  const int wr = wv >> 1, wc = wv & 1;

  f32x4 acc[4][4];
#pragma unroll
  for (int m = 0; m < 4; ++m)
#pragma unroll
    for (int n = 0; n < 4; ++n) acc[m][n] = (f32x4){0.f, 0.f, 0.f, 0.f};

  core128h(xh, Bh, AhL, BhL, row0, col0, wv, lane, acc);

  const int cbase = col0 + wc * 64;
  const int h = cbase >> 6;
  if (mode < 2) {
    const float scale = (mode == 0) ? 0.18033688f : 1.0f;   // 1/8 * log2(e) folded for Q
    const float2* rt2 = (const float2*)rt;
#pragma unroll
    for (int n = 0; n < 2; ++n) {
      const int d = n * 16 + l15;
      const float b0 = bias[cbase + d], b1 = bias[cbase + d + 32];
#pragma unroll
      for (int m = 0; m < 4; ++m)
#pragma unroll
        for (int rr = 0; rr < 4; ++rr) {
          int R = row0 + wr * 64 + m * 16 + g * 4 + rr;
          int bI = R >> 11, t = R & (Tt - 1);
          float2 cssn = rt2[t * 32 + d];           // coalesced 8B table load
          float v0 = acc[m][n][rr] + b0, v1 = acc[m][n + 2][rr] + b1;
          size_t base = (((size_t)(bI * Hh + h) * Tt + t) << 6) + d;
          Y[base]      = f2h((v0 * cssn.x - v1 * cssn.y) * scale);
          Y[base + 32] = f2h((v1 * cssn.x + v0 * cssn.y) * scale);
        }
    }
  } else {
    // V: write transposed [B,H,D,T] fp16
#pragma unroll
    for (int n = 0; n < 2; ++n) {
      const int d = n * 16 + l15;
      const float b0 = bias[cbase + d], b1 = bias[cbase + d + 32];
#pragma unroll
      for (int m = 0; m < 4; ++m) {
        int R = row0 + wr * 64 + m * 16 + g * 4;
        int bI = R >> 11, t = R & (Tt - 1);
        short4v s0, s1;
#pragma unroll
        for (int rr = 0; rr < 4; ++rr) {
          s0[rr] = f2h(acc[m][n][rr] + b0);
          s1[rr] = f2h(acc[m][n + 2][rr] + b1);
        }
        size_t base = ((size_t)(bI * Hh + h) * Dd);
        *(short4v*)(Y + (base + d) * Tt + t)      = s0;
        *(short4v*)(Y + (base + d + 32) * Tt + t) = s1;
      }
    }
  }
}

// ---------------- final output GEMM (fp16 core, fp32 out) ----------------
__global__ __launch_bounds__(256, 3) void gemm_out(const short* __restrict__ ah,
                                                   const short* __restrict__ WTo,
                                                   const float* __restrict__ bias,
                                                   float* __restrict__ Y) {
  __shared__ short AhL[8192], BhL[8192];
  const int bid = blockIdx.x;
  const int nid = ((bid & 7) << 5) | (bid >> 3);
  const int row0 = (nid >> 3) * 128, col0 = (nid & 7) * 128;
  const int lane = threadIdx.x & 63, wv = threadIdx.x >> 6;
  const int l15 = lane & 15, g = lane >> 4;
  const int wr = wv >> 1, wc = wv & 1;

  f32x4 acc[4][4];
#pragma unroll
  for (int m = 0; m < 4; ++m)
#pragma unroll
    for (int n = 0; n < 4; ++n) acc[m][n] = (f32x4){0.f, 0.f, 0.f, 0.f};

  core128h(ah, WTo, AhL, BhL, row0, col0, wv, lane, acc);

  const int cbase = col0 + wc * 64;
#pragma unroll
  for (int n = 0; n < 2; ++n) {
    const int ccol = cbase + n * 16 + l15;
    const float b0 = bias[ccol], b1 = bias[ccol + 32];
#pragma unroll
    for (int m = 0; m < 4; ++m)
#pragma unroll
      for (int rr = 0; rr < 4; ++rr) {
        int R = row0 + wr * 64 + m * 16 + g * 4 + rr;
        Y[(size_t)R * Cc + ccol]      = acc[m][n][rr] + b0;
        Y[(size_t)R * Cc + ccol + 32] = acc[m][n + 2][rr] + b1;
      }
  }
}

// ================= MFMA flash attention (r16, unchanged) =============
static __device__ const int JQ[27] = {11, 0,0, 1,1, 2,2, 3,3, 4,4, 12, 5,5,
                                      6,6, 13, 7,7, 8,8, 14, 9,9, 15, 10,10};
static __device__ const int JK[27] = {0, 0,1, 0,1, 0,1, 0,1, 0,1, 0, 0,1,
                                      0,1, 0, 0,1, 0,1, 0, 0,1, 0, 0,1};

__global__ __launch_bounds__(256, 4) void attn_mfma(const short* __restrict__ q,
                                                    const short* __restrict__ k,
                                                    const short* __restrict__ vT,
                                                    short* __restrict__ ah,
                                                    float* __restrict__ yb,
                                                    float* __restrict__ side) {
  const int n = blockIdx.x;           // 864
  const int xcd = n & 7;
  const int t7 = n >> 3;              // 0..107
  const int bhj = t7 / 27;
  const int j = t7 - bhj * 27;
  const int bh = xcd * 4 + bhj;
  const int Q = JQ[j];
  const int kh = JK[j];
  const int split = (Q <= 10);
  const int q0 = Q * 128;

  const int tid = threadIdx.x;
  const int lane = tid & 63;
  const int wv = tid >> 6;
  const int l31 = lane & 31;
  const int hb = lane >> 5;
  const int qbase = q0 + wv * 32;
  const int tq = qbase + l31;

  const short* qgb = q + (size_t)bh * Tt * Dd;
  const short* kgb = k + (size_t)bh * Tt * Dd;
  const short* vgb = vT + (size_t)bh * Dd * Tt;

  const short* qp = qgb + (size_t)tq * Dd + 8 * hb;
  half8v qf[4];
#pragma unroll
  for (int i = 0; i < 4; ++i) qf[i] = __builtin_bit_cast(half8v, *(const short8v*)(qp + 16 * i));

  __shared__ short Klds[2][4096];
  __shared__ short Vt[2][4096];

  const int r8 = lane >> 3;
  const size_t ksrc0 = (size_t)(wv * 16 + r8) * Dd + (((lane & 7) ^ r8) << 3);
  const size_t ksrc1 = ksrc0 + (size_t)8 * Dd;
  const int vlog = ((lane & 7) - r8) & 7;
  const size_t vsrc0 = (size_t)(wv * 16 + r8) * Tt + (vlog << 3);
  const size_t vsrc1 = vsrc0 + (size_t)8 * Tt;

#define STAGE64(BUF, JT)                                                     \
  {                                                                          \
    gll16(kgb + (size_t)(JT) * Dd + ksrc0, &Klds[BUF][wv * 1024]);           \
    gll16(kgb + (size_t)(JT) * Dd + ksrc1, &Klds[BUF][wv * 1024 + 512]);     \
    gll16(vgb + vsrc0 + (JT), &Vt[BUF][wv * 1024]);                          \
    gll16(vgb + vsrc1 + (JT), &Vt[BUF][wv * 1024 + 512]);                    \
  }

  int koff[4], voff[4];
#pragma unroll
  for (int i = 0; i < 4; ++i) {
    koff[i] = l31 * 64 + (((2 * i + hb) ^ (l31 & 7)) << 3);
    voff[i] = l31 * 64 + ((((2 * i + hb) + (l31 & 7)) & 7) << 3);
  }

  f32x16 oacc[2];
#pragma unroll
  for (int t = 0; t < 2; ++t)
#pragma unroll
    for (int r = 0; r < 16; ++r) oacc[t][r] = 0.f;
  float lrun = 0.f;

  const int cs0 = (q0 >= 512) ? (q0 - 511) : 0;
  const int cstart = cs0 & ~63;
  const int nch_b = (Tt - cstart) >> 6;
  const int lower = (nch_b + 1) >> 1;
  const int mystart = cstart + ((split && kh) ? (lower << 6) : 0);
  const int myn = split ? (kh ? nch_b - lower : lower) : nch_b;

  STAGE64(0, mystart);
  __syncthreads();

  int cur = 0;
  for (int ci = 0; ci < myn; ++ci) {
    const int jt = mystart + (ci << 6);

    if (ci + 1 < myn) STAGE64(cur ^ 1, jt + 64);

    const short* kbuf = &Klds[cur][0];
    f32x16 seA, seB;
#pragma unroll
    for (int r = 0; r < 16; ++r) { seA[r] = 0.f; seB[r] = 0.f; }
    __builtin_amdgcn_s_setprio(1);
#pragma unroll
    for (int i = 0; i < 4; ++i) {
      half8v kfA = __builtin_bit_cast(half8v, *(short8v*)&kbuf[koff[i]]);
      seA = __builtin_amdgcn_mfma_f32_32x32x16_f16(kfA, qf[i], seA, 0, 0, 0);
    }
#pragma unroll
    for (int i = 0; i < 4; ++i) {
      half8v kfB = __builtin_bit_cast(half8v, *(short8v*)&kbuf[koff[i] + 2048]);
      seB = __builtin_amdgcn_mfma_f32_32x32x16_f16(kfB, qf[i], seB, 0, 0, 0);
    }
    __builtin_amdgcn_s_setprio(0);

    if (jt < qbase - 480) {
      int th = tq - 511 - jt;
#pragma unroll
      for (int r = 0; r < 16; ++r) {
        int row = (r & 3) + 8 * (r >> 2) + 4 * hb;
        if (row < th) seA[r] = -1e30f;
        if (32 + row < th) seB[r] = -1e30f;
      }
    }

    float pA[16], pB[16];
#pragma unroll
    for (int r = 0; r < 16; ++r) {
      asm("v_exp_f32 %0, %1" : "=v"(pA[r]) : "v"(seA[r]));
      asm("v_exp_f32 %0, %1" : "=v"(pB[r]) : "v"(seB[r]));
    }
    float t0 = 0.f, t1 = 0.f, t2 = 0.f, t3 = 0.f;
#pragma unroll
    for (int r = 0; r < 16; r += 4) {
      t0 += pA[r];     t1 += pA[r + 1]; t2 += pA[r + 2]; t3 += pA[r + 3];
      t0 += pB[r];     t1 += pB[r + 1]; t2 += pB[r + 2]; t3 += pB[r + 3];
    }
    float psum = (t0 + t1) + (t2 + t3);
    psum += __shfl_xor(psum, 32);
    lrun += psum;

    unsigned pa[8], pb[8];
#pragma unroll
    for (int i = 0; i < 8; ++i) {
      pa[i] = __builtin_bit_cast(unsigned, __builtin_amdgcn_cvt_pkrtz(pA[2 * i], pA[2 * i + 1]));
      pb[i] = __builtin_bit_cast(unsigned, __builtin_amdgcn_cvt_pkrtz(pB[2 * i], pB[2 * i + 1]));
    }
    asm volatile("v_permlane32_swap_b32 %0, %1" : "+v"(pa[0]), "+v"(pa[2]));
    asm volatile("v_permlane32_swap_b32 %0, %1" : "+v"(pa[1]), "+v"(pa[3]));
    asm volatile("v_permlane32_swap_b32 %0, %1" : "+v"(pa[4]), "+v"(pa[6]));
    asm volatile("v_permlane32_swap_b32 %0, %1" : "+v"(pa[5]), "+v"(pa[7]));
    asm volatile("v_permlane32_swap_b32 %0, %1" : "+v"(pb[0]), "+v"(pb[2]));
    asm volatile("v_permlane32_swap_b32 %0, %1" : "+v"(pb[1]), "+v"(pb[3]));
    asm volatile("v_permlane32_swap_b32 %0, %1" : "+v"(pb[4]), "+v"(pb[6]));
    asm volatile("v_permlane32_swap_b32 %0, %1" : "+v"(pb[5]), "+v"(pb[7]));
    uint4v fA0, fA1, fB0, fB1;
    fA0[0] = pa[0]; fA0[1] = pa[1]; fA0[2] = pa[2]; fA0[3] = pa[3];
    fA1[0] = pa[4]; fA1[1] = pa[5]; fA1[2] = pa[6]; fA1[3] = pa[7];
    fB0[0] = pb[0]; fB0[1] = pb[1]; fB0[2] = pb[2]; fB0[3] = pb[3];
    fB1[0] = pb[4]; fB1[1] = pb[5]; fB1[2] = pb[6]; fB1[3] = pb[7];
    half8v pfA0 = __builtin_bit_cast(half8v, fA0);
    half8v pfA1 = __builtin_bit_cast(half8v, fA1);
    half8v pfB0 = __builtin_bit_cast(half8v, fB0);
    half8v pfB1 = __builtin_bit_cast(half8v, fB1);

    const short* vbuf = &Vt[cur][0];
    __builtin_amdgcn_s_setprio(1);
#pragma unroll
    for (int t = 0; t < 2; ++t) {
      const int ro = t * 2048;
      half8v v0 = __builtin_bit_cast(half8v, *(short8v*)&vbuf[voff[0] + ro]);
      half8v v1 = __builtin_bit_cast(half8v, *(short8v*)&vbuf[voff[1] + ro]);
      half8v v2 = __builtin_bit_cast(half8v, *(short8v*)&vbuf[voff[2] + ro]);
      half8v v3 = __builtin_bit_cast(half8v, *(short8v*)&vbuf[voff[3] + ro]);
      oacc[t] = __builtin_amdgcn_mfma_f32_32x32x16_f16(v0, pfA0, oacc[t], 0, 0, 0);
      oacc[t] = __builtin_amdgcn_mfma_f32_32x32x16_f16(v1, pfA1, oacc[t], 0, 0, 0);
      oacc[t] = __builtin_amdgcn_mfma_f32_32x32x16_f16(v2, pfB0, oacc[t], 0, 0, 0);
      oacc[t] = __builtin_amdgcn_mfma_f32_32x32x16_f16(v3, pfB1, oacc[t], 0, 0, 0);
    }
    __builtin_amdgcn_s_setprio(0);

    __syncthreads();
    cur ^= 1;
  }

  const float invl = 1.f / lrun;
  const int row = bh * Tt + tq;
  if (split && hb == 0) side[kh * 65536 + row] = lrun;
  const int bI = bh >> 4, hd = bh & 15;
  if (!split || kh == 0) {
    short* op = ah + ((size_t)(bI * Tt + tq)) * Cc + hd * Dd;
#pragma unroll
    for (int t = 0; t < 2; ++t)
#pragma unroll
      for (int rq = 0; rq < 4; ++rq) {
        short4v hv;
#pragma unroll
        for (int rr = 0; rr < 4; ++rr) hv[rr] = f2h(oacc[t][4 * rq + rr] * invl);
        *(short4v*)(op + 32 * t + 8 * rq + 4 * hb) = hv;
      }
  } else {
    float* yp = yb + (size_t)row * 64;
#pragma unroll
    for (int t = 0; t < 2; ++t)
#pragma unroll
      for (int rq = 0; rq < 4; ++rq) {
        f32x4 o4;
#pragma unroll
        for (int rr = 0; rr < 4; ++rr) o4[rr] = oacc[t][4 * rq + rr] * invl;
        *(f32x4*)(yp + 32 * t + 8 * rq + 4 * hb) = o4;
      }
  }
}

// ---------------- merge the two key-halves for split tiles (tq < 1408) ----------------
__global__ __launch_bounds__(256) void attn_merge(short* __restrict__ ah,
                                                  const float* __restrict__ yb,
                                                  const float* __restrict__ side) {
  const int bh = blockIdx.y;
  const int idx = blockIdx.x * 256 + threadIdx.x;
  const int tq = idx >> 2;
  const int qd = (idx & 3) << 4;
  const int row = bh * Tt + tq;
  const float l0 = side[row], l1 = side[65536 + row];
  const float inv = 1.f / (l0 + l1);
  const float a0 = l0 * inv, a1 = l1 * inv;

  const int bI = bh >> 4, hd = bh & 15;
  short* op = ah + ((size_t)(bI * Tt + tq)) * Cc + hd * Dd + qd;
  const float* yp = yb + (size_t)row * 64 + qd;

  short8v h0 = *(short8v*)op, h1 = *(short8v*)(op + 8);
  short8v o0, o1;
#pragma unroll
  for (int e = 0; e < 8; ++e) o0[e] = f2h(a0 * h2f(h0[e]) + a1 * yp[e]);
#pragma unroll
  for (int e = 0; e < 8; ++e) o1[e] = f2h(a0 * h2f(h1[e]) + a1 * yp[8 + e]);
  *(short8v*)op = o0;
  *(short8v*)(op + 8) = o1;
}

extern "C" void kernel_launch(void* const* d_in, const int* in_sizes, int n_in,
                              void* d_out, int out_size, void* d_ws, size_t ws_size,
                              hipStream_t stream) {
  const float* x  = (const float*)d_in[0];
  const float* Wq = (const float*)d_in[1];
  const float* bq = (const float*)d_in[2];
  const float* Wk = (const float*)d_in[3];
  const float* bk = (const float*)d_in[4];
  const float* Wv = (const float*)d_in[5];
  const float* bv = (const float*)d_in[6];
  const float* Wo = (const float*)d_in[7];
  const float* bo = (const float*)d_in[8];

  short* ws16 = (short*)d_ws;
  short* xh  = ws16;                  // 8MB fp16 x
  short* WTh = ws16 + 4194304;        // 8MB: Wq,Wk,Wv,Wo transposed fp16
  short* qb  = ws16 + 8388608;        // 8MB fp16 [B,H,T,D]
  short* kb  = ws16 + 12582912;       // 8MB fp16 [B,H,T,D]
  short* vb  = ws16 + 16777216;       // 8MB fp16 [B,H,D,T] (V transposed)
  short* ah  = ws16 + 20971520;       // 8MB fp16 attn out [B,T,C]
  float* yb   = (float*)(ws16 + 25165824);  // 16.78MB fp32 kh=1 partials [65536][64]
  float* side = yb + 4194304;               // 0.5MB: [kh][65536] = l
  float* rt   = side + 131072;              // 0.5MB rope table [2048][32] float2

  prep<<<3328, 256, 0, stream>>>(x, Wq, Wk, Wv, Wo, xh, WTh, rt);

  gemm_qkv<<<dim3(256, 3), 256, 0, stream>>>(xh, WTh, bq, bk, bv, rt, qb, kb, vb);

  attn_mfma<<<864, 256, 0, stream>>>(qb, kb, vb, ah, yb, side);
  attn_merge<<<dim3(22, 32), 256, 0, stream>>>(ah, yb, side);

  gemm_out<<<256, 256, 0, stream>>>(ah, WTh + 3 * 1048576, bo, (float*)d_out);
}

// Round 18
// 114.339 us; speedup vs baseline: 1.3455x; 1.0310x over previous
//
#include <hip/hip_runtime.h>
#include <hip/hip_bf16.h>
#include <math.h>

#define Bsz 2
#define Tt  2048
#define Cc  1024
#define Hh  16
#define Dd  64

typedef __attribute__((ext_vector_type(8))) short short8v;
typedef __attribute__((ext_vector_type(4))) short short4v;
typedef __attribute__((ext_vector_type(8))) _Float16 half8v;
typedef __attribute__((ext_vector_type(4))) float f32x4;
typedef __attribute__((ext_vector_type(16))) float f32x16;
typedef __attribute__((ext_vector_type(4))) unsigned int uint4v;

static __device__ __forceinline__ short f2h(float f) {
  _Float16 h = (_Float16)f;   // v_cvt_f16_f32 (RNE)
  return __builtin_bit_cast(short, h);
}
static __device__ __forceinline__ float h2f(short s) {
  _Float16 h = __builtin_bit_cast(_Float16, s);
  return (float)h;
}
static __device__ __forceinline__ void gll16(const void* g, void* l) {
  __builtin_amdgcn_global_load_lds((const __attribute__((address_space(1))) unsigned int*)g,
                                   (__attribute__((address_space(3))) unsigned int*)l, 16, 0, 0);
}

// ---------------- fused prepass: cast x, cast+transpose W, rope table ----------------
__global__ __launch_bounds__(256) void prep(const float* __restrict__ x,
                                            const float* __restrict__ Wq,
                                            const float* __restrict__ Wk,
                                            const float* __restrict__ Wv,
                                            const float* __restrict__ Wo,
                                            short* __restrict__ xh,
                                            short* __restrict__ WTh,
                                            float* __restrict__ rt) {
  __shared__ float T[64][68];
  const int bid = blockIdx.x;
  const int tid = threadIdx.x;

  if (bid < 2048) {           // ---- cast x ----
    int t = bid * 256 + tid;
    const float* s = x + (size_t)t * 8;
    float4 a = *(const float4*)s, b = *(const float4*)(s + 4);
    short8v h;
    h[0] = f2h(a.x); h[1] = f2h(a.y); h[2] = f2h(a.z); h[3] = f2h(a.w);
    h[4] = f2h(b.x); h[5] = f2h(b.y); h[6] = f2h(b.z); h[7] = f2h(b.w);
    *(short8v*)(xh + (size_t)t * 8) = h;
  } else if (bid < 3072) {    // ---- cast + transpose W ----
    const int z = (bid - 2048) >> 8;
    const int slot = (bid - 2048) & 255;
    const float* W = z == 0 ? Wq : z == 1 ? Wk : z == 2 ? Wv : Wo;
    short* oh = WTh + (size_t)z * 1048576;
    const int n0 = (slot & 15) * 64, k0 = (slot >> 4) * 64;
#pragma unroll
    for (int i = 0; i < 4; ++i) {
      int s2 = tid + i * 256;
      int r = s2 >> 4, c4 = (s2 & 15) << 2;
      *(float4*)&T[r][c4] = *(const float4*)(W + (size_t)(k0 + r) * Cc + n0 + c4);
    }
    __syncthreads();
#pragma unroll
    for (int i = 0; i < 2; ++i) {
      int s2 = tid + i * 256;
      int nl = s2 >> 3, ks = (s2 & 7) << 3;
      short8v h;
#pragma unroll
      for (int e = 0; e < 8; ++e) h[e] = f2h(T[ks + e][nl]);
      *(short8v*)(oh + (size_t)(n0 + nl) * Cc + k0 + ks) = h;
    }
  } else {                    // ---- rope table ----
    int idx = (bid - 3072) * 256 + tid;   // [0, 65536)
    int t = idx >> 5, p = idx & 31;
    float inv = exp2f(-(float)p * (13.2877123795494f / 32.f));
    float sn, cs;
    sincosf((float)t * inv, &sn, &cs);
    float2 v; v.x = cs; v.y = sn;
    *(float2*)(rt + (size_t)idx * 2) = v;
  }
}

// ================= 128x128 fp16 GEMM core, BK=64 =================
__device__ __forceinline__ void core128h(const short* __restrict__ Ah,
                                         const short* __restrict__ Bh,
                                         short* AhL, short* BhL,
                                         int row0, int col0, int wv, int lane, f32x4 acc[4][4]) {
  const int l15 = lane & 15, g = lane >> 4;
  const int wr = wv >> 1, wc = wv & 1;

  const int r8 = lane >> 3;
  const int sch = ((lane & 7) ^ r8) << 3;
  size_t aoff[4], boff[4];
#pragma unroll
  for (int gi = 0; gi < 4; ++gi) {
    aoff[gi] = (size_t)(row0 + wv * 32 + 8 * gi + r8) * Cc + sch;
    boff[gi] = (size_t)(col0 + wv * 32 + 8 * gi + r8) * Cc + sch;
  }
  short* dA = AhL + wv * 2048;
  short* dB = BhL + wv * 2048;

  int aL[4][2], bL[4][2];
#pragma unroll
  for (int m = 0; m < 4; ++m)
#pragma unroll
    for (int s = 0; s < 2; ++s) {
      aL[m][s] = (wr * 64 + m * 16 + l15) * 64 + (((4 * s + g) ^ (l15 & 7)) << 3);
      bL[m][s] = (wc * 64 + m * 16 + l15) * 64 + (((4 * s + g) ^ (l15 & 7)) << 3);
    }

  for (int k0 = 0; k0 < Cc; k0 += 64) {
    __syncthreads();
#pragma unroll
    for (int gi = 0; gi < 4; ++gi) {
      gll16(Ah + aoff[gi] + k0, dA + gi * 512);
      gll16(Bh + boff[gi] + k0, dB + gi * 512);
    }
    __syncthreads();
#pragma unroll
    for (int s = 0; s < 2; ++s) {
      half8v a[4], b[4];
#pragma unroll
      for (int m = 0; m < 4; ++m) a[m] = __builtin_bit_cast(half8v, *(short8v*)&AhL[aL[m][s]]);
#pragma unroll
      for (int n = 0; n < 4; ++n) b[n] = __builtin_bit_cast(half8v, *(short8v*)&BhL[bL[n][s]]);
#pragma unroll
      for (int m = 0; m < 4; ++m)
#pragma unroll
        for (int n = 0; n < 4; ++n)
          acc[m][n] = __builtin_amdgcn_mfma_f32_16x16x32_f16(a[m], b[n], acc[m][n], 0, 0, 0);
    }
  }
}

// ---------------- QKV projection GEMM (fp16), rope via table, V transposed ----------------
__global__ __launch_bounds__(256, 3) void gemm_qkv(const short* __restrict__ xh,
                                                   const short* __restrict__ WTh,
                                                   const float* __restrict__ bq,
                                                   const float* __restrict__ bk,
                                                   const float* __restrict__ bv,
                                                   const float* __restrict__ rt,
                                                   short* __restrict__ qb,
                                                   short* __restrict__ kb,
                                                   short* __restrict__ vb) {
  __shared__ short AhL[8192], BhL[8192];
  const int mode = blockIdx.y;
  const short* Bh = WTh + (size_t)mode * 1048576;
  const float* bias = mode == 0 ? bq : mode == 1 ? bk : bv;
  short* Y = mode == 0 ? qb : mode == 1 ? kb : vb;

  const int bid = blockIdx.x;
  const int nid = ((bid & 7) << 5) | (bid >> 3);
  const int row0 = (nid >> 3) * 128, col0 = (nid & 7) * 128;
  const int lane = threadIdx.x & 63, wv = threadIdx.x >> 6;
  const int l15 = lane & 15, g = lane >> 4;
  const int wr = wv >> 1, wc = wv & 1;

  f32x4 acc[4][4];
#pragma unroll
  for (int m = 0; m < 4; ++m)
#pragma unroll
    for (int n = 0; n < 4; ++n) acc[m][n] = (f32x4){0.f, 0.f, 0.f, 0.f};

  core128h(xh, Bh, AhL, BhL, row0, col0, wv, lane, acc);

  const int cbase = col0 + wc * 64;
  const int h = cbase >> 6;
  if (mode < 2) {
    const float scale = (mode == 0) ? 0.18033688f : 1.0f;   // 1/8 * log2(e) folded for Q
    const float2* rt2 = (const float2*)rt;
#pragma unroll
    for (int n = 0; n < 2; ++n) {
      const int d = n * 16 + l15;
      const float b0 = bias[cbase + d], b1 = bias[cbase + d + 32];
#pragma unroll
      for (int m = 0; m < 4; ++m)
#pragma unroll
        for (int rr = 0; rr < 4; ++rr) {
          int R = row0 + wr * 64 + m * 16 + g * 4 + rr;
          int bI = R >> 11, t = R & (Tt - 1);
          float2 cssn = rt2[t * 32 + d];
          float v0 = acc[m][n][rr] + b0, v1 = acc[m][n + 2][rr] + b1;
          size_t base = (((size_t)(bI * Hh + h) * Tt + t) << 6) + d;
          Y[base]      = f2h((v0 * cssn.x - v1 * cssn.y) * scale);
          Y[base + 32] = f2h((v1 * cssn.x + v0 * cssn.y) * scale);
        }
    }
  } else {
    // V: write transposed [B,H,D,T] fp16
#pragma unroll
    for (int n = 0; n < 2; ++n) {
      const int d = n * 16 + l15;
      const float b0 = bias[cbase + d], b1 = bias[cbase + d + 32];
#pragma unroll
      for (int m = 0; m < 4; ++m) {
        int R = row0 + wr * 64 + m * 16 + g * 4;
        int bI = R >> 11, t = R & (Tt - 1);
        short4v s0, s1;
#pragma unroll
        for (int rr = 0; rr < 4; ++rr) {
          s0[rr] = f2h(acc[m][n][rr] + b0);
          s1[rr] = f2h(acc[m][n + 2][rr] + b1);
        }
        size_t base = ((size_t)(bI * Hh + h) * Dd);
        *(short4v*)(Y + (base + d) * Tt + t)      = s0;
        *(short4v*)(Y + (base + d + 32) * Tt + t) = s1;
      }
    }
  }
}

// ---------------- final output GEMM (fp16 core, fp32 out) ----------------
__global__ __launch_bounds__(256, 3) void gemm_out(const short* __restrict__ ah,
                                                   const short* __restrict__ WTo,
                                                   const float* __restrict__ bias,
                                                   float* __restrict__ Y) {
  __shared__ short AhL[8192], BhL[8192];
  const int bid = blockIdx.x;
  const int nid = ((bid & 7) << 5) | (bid >> 3);
  const int row0 = (nid >> 3) * 128, col0 = (nid & 7) * 128;
  const int lane = threadIdx.x & 63, wv = threadIdx.x >> 6;
  const int l15 = lane & 15, g = lane >> 4;
  const int wr = wv >> 1, wc = wv & 1;

  f32x4 acc[4][4];
#pragma unroll
  for (int m = 0; m < 4; ++m)
#pragma unroll
    for (int n = 0; n < 4; ++n) acc[m][n] = (f32x4){0.f, 0.f, 0.f, 0.f};

  core128h(ah, WTo, AhL, BhL, row0, col0, wv, lane, acc);

  const int cbase = col0 + wc * 64;
#pragma unroll
  for (int n = 0; n < 2; ++n) {
    const int ccol = cbase + n * 16 + l15;
    const float b0 = bias[ccol], b1 = bias[ccol + 32];
#pragma unroll
    for (int m = 0; m < 4; ++m)
#pragma unroll
      for (int rr = 0; rr < 4; ++rr) {
        int R = row0 + wr * 64 + m * 16 + g * 4 + rr;
        Y[(size_t)R * Cc + ccol]      = acc[m][n][rr] + b0;
        Y[(size_t)R * Cc + ccol + 32] = acc[m][n + 2][rr] + b1;
      }
  }
}

// ================= MFMA flash attention: ALL q-tiles split-K=2 =================
// 32 jobs/bh (lengths 16..5 sorted descending), grid 1024 = 4 blocks/CU.
// Decode bhj = t7&3, j = t7>>2 so each CU's 4 jobs are {j, j+8, j+16, j+24}
// of the sorted list -> per-CU chunk load 43..52 vs mean 47.5 (1.09x).
// kh=0 writes fp16 ah + side[0]; kh=1 writes fp32 yb + side[1]; merge all rows.
static __device__ const int JQ2[32] = {0,0, 1,1, 2,2, 3,3, 4,4, 5,5, 6,6, 7,7,
                                       8,8, 9,9, 10,10, 11,11, 12,12, 13,13,
                                       14,14, 15,15};
static __device__ const int JK2[32] = {0,1, 0,1, 0,1, 0,1, 0,1, 0,1, 0,1, 0,1,
                                       0,1, 0,1, 0,1, 0,1, 0,1, 0,1, 0,1, 0,1};

__global__ __launch_bounds__(256, 4) void attn_mfma(const short* __restrict__ q,
                                                    const short* __restrict__ k,
                                                    const short* __restrict__ vT,
                                                    short* __restrict__ ah,
                                                    float* __restrict__ yb,
                                                    float* __restrict__ side) {
  const int n = blockIdx.x;           // 1024
  const int xcd = n & 7;
  const int t7 = n >> 3;              // 0..127
  const int bhj = t7 & 3;
  const int j = t7 >> 2;              // 0..31
  const int bh = xcd * 4 + bhj;
  const int Q = JQ2[j];
  const int kh = JK2[j];
  const int q0 = Q * 128;

  const int tid = threadIdx.x;
  const int lane = tid & 63;
  const int wv = tid >> 6;
  const int l31 = lane & 31;
  const int hb = lane >> 5;
  const int qbase = q0 + wv * 32;
  const int tq = qbase + l31;

  const short* qgb = q + (size_t)bh * Tt * Dd;
  const short* kgb = k + (size_t)bh * Tt * Dd;
  const short* vgb = vT + (size_t)bh * Dd * Tt;

  const short* qp = qgb + (size_t)tq * Dd + 8 * hb;
  half8v qf[4];
#pragma unroll
  for (int i = 0; i < 4; ++i) qf[i] = __builtin_bit_cast(half8v, *(const short8v*)(qp + 16 * i));

  __shared__ short Klds[2][4096];
  __shared__ short Vt[2][4096];

  const int r8 = lane >> 3;
  const size_t ksrc0 = (size_t)(wv * 16 + r8) * Dd + (((lane & 7) ^ r8) << 3);
  const size_t ksrc1 = ksrc0 + (size_t)8 * Dd;
  const int vlog = ((lane & 7) - r8) & 7;
  const size_t vsrc0 = (size_t)(wv * 16 + r8) * Tt + (vlog << 3);
  const size_t vsrc1 = vsrc0 + (size_t)8 * Tt;

#define STAGE64(BUF, JT)                                                     \
  {                                                                          \
    gll16(kgb + (size_t)(JT) * Dd + ksrc0, &Klds[BUF][wv * 1024]);           \
    gll16(kgb + (size_t)(JT) * Dd + ksrc1, &Klds[BUF][wv * 1024 + 512]);     \
    gll16(vgb + vsrc0 + (JT), &Vt[BUF][wv * 1024]);                          \
    gll16(vgb + vsrc1 + (JT), &Vt[BUF][wv * 1024 + 512]);                    \
  }

  int koff[4], voff[4];
#pragma unroll
  for (int i = 0; i < 4; ++i) {
    koff[i] = l31 * 64 + (((2 * i + hb) ^ (l31 & 7)) << 3);
    voff[i] = l31 * 64 + ((((2 * i + hb) + (l31 & 7)) & 7) << 3);
  }

  f32x16 oacc[2];
#pragma unroll
  for (int t = 0; t < 2; ++t)
#pragma unroll
    for (int r = 0; r < 16; ++r) oacc[t][r] = 0.f;
  float lrun = 0.f;

  const int cs0 = (q0 >= 512) ? (q0 - 511) : 0;
  const int cstart = cs0 & ~63;
  const int nch_b = (Tt - cstart) >> 6;
  const int lower = (nch_b + 1) >> 1;
  const int mystart = cstart + (kh ? (lower << 6) : 0);
  const int myn = kh ? (nch_b - lower) : lower;

  STAGE64(0, mystart);
  __syncthreads();

  int cur = 0;
  for (int ci = 0; ci < myn; ++ci) {
    const int jt = mystart + (ci << 6);

    if (ci + 1 < myn) STAGE64(cur ^ 1, jt + 64);

    const short* kbuf = &Klds[cur][0];
    f32x16 seA, seB;
#pragma unroll
    for (int r = 0; r < 16; ++r) { seA[r] = 0.f; seB[r] = 0.f; }
    __builtin_amdgcn_s_setprio(1);
#pragma unroll
    for (int i = 0; i < 4; ++i) {
      half8v kfA = __builtin_bit_cast(half8v, *(short8v*)&kbuf[koff[i]]);
      seA = __builtin_amdgcn_mfma_f32_32x32x16_f16(kfA, qf[i], seA, 0, 0, 0);
    }
#pragma unroll
    for (int i = 0; i < 4; ++i) {
      half8v kfB = __builtin_bit_cast(half8v, *(short8v*)&kbuf[koff[i] + 2048]);
      seB = __builtin_amdgcn_mfma_f32_32x32x16_f16(kfB, qf[i], seB, 0, 0, 0);
    }
    __builtin_amdgcn_s_setprio(0);

    if (jt < qbase - 480) {
      int th = tq - 511 - jt;
#pragma unroll
      for (int r = 0; r < 16; ++r) {
        int row = (r & 3) + 8 * (r >> 2) + 4 * hb;
        if (row < th) seA[r] = -1e30f;
        if (32 + row < th) seB[r] = -1e30f;
      }
    }

    float pA[16], pB[16];
#pragma unroll
    for (int r = 0; r < 16; ++r) {
      asm("v_exp_f32 %0, %1" : "=v"(pA[r]) : "v"(seA[r]));
      asm("v_exp_f32 %0, %1" : "=v"(pB[r]) : "v"(seB[r]));
    }
    float t0 = 0.f, t1 = 0.f, t2 = 0.f, t3 = 0.f;
#pragma unroll
    for (int r = 0; r < 16; r += 4) {
      t0 += pA[r];     t1 += pA[r + 1]; t2 += pA[r + 2]; t3 += pA[r + 3];
      t0 += pB[r];     t1 += pB[r + 1]; t2 += pB[r + 2]; t3 += pB[r + 3];
    }
    float psum = (t0 + t1) + (t2 + t3);
    psum += __shfl_xor(psum, 32);
    lrun += psum;

    unsigned pa[8], pb[8];
#pragma unroll
    for (int i = 0; i < 8; ++i) {
      pa[i] = __builtin_bit_cast(unsigned, __builtin_amdgcn_cvt_pkrtz(pA[2 * i], pA[2 * i + 1]));
      pb[i] = __builtin_bit_cast(unsigned, __builtin_amdgcn_cvt_pkrtz(pB[2 * i], pB[2 * i + 1]));
    }
    asm volatile("v_permlane32_swap_b32 %0, %1" : "+v"(pa[0]), "+v"(pa[2]));
    asm volatile("v_permlane32_swap_b32 %0, %1" : "+v"(pa[1]), "+v"(pa[3]));
    asm volatile("v_permlane32_swap_b32 %0, %1" : "+v"(pa[4]), "+v"(pa[6]));
    asm volatile("v_permlane32_swap_b32 %0, %1" : "+v"(pa[5]), "+v"(pa[7]));
    asm volatile("v_permlane32_swap_b32 %0, %1" : "+v"(pb[0]), "+v"(pb[2]));
    asm volatile("v_permlane32_swap_b32 %0, %1" : "+v"(pb[1]), "+v"(pb[3]));
    asm volatile("v_permlane32_swap_b32 %0, %1" : "+v"(pb[4]), "+v"(pb[6]));
    asm volatile("v_permlane32_swap_b32 %0, %1" : "+v"(pb[5]), "+v"(pb[7]));
    uint4v fA0, fA1, fB0, fB1;
    fA0[0] = pa[0]; fA0[1] = pa[1]; fA0[2] = pa[2]; fA0[3] = pa[3];
    fA1[0] = pa[4]; fA1[1] = pa[5]; fA1[2] = pa[6]; fA1[3] = pa[7];
    fB0[0] = pb[0]; fB0[1] = pb[1]; fB0[2] = pb[2]; fB0[3] = pb[3];
    fB1[0] = pb[4]; fB1[1] = pb[5]; fB1[2] = pb[6]; fB1[3] = pb[7];
    half8v pfA0 = __builtin_bit_cast(half8v, fA0);
    half8v pfA1 = __builtin_bit_cast(half8v, fA1);
    half8v pfB0 = __builtin_bit_cast(half8v, fB0);
    half8v pfB1 = __builtin_bit_cast(half8v, fB1);

    const short* vbuf = &Vt[cur][0];
    __builtin_amdgcn_s_setprio(1);
#pragma unroll
    for (int t = 0; t < 2; ++t) {
      const int ro = t * 2048;
      half8v v0 = __builtin_bit_cast(half8v, *(short8v*)&vbuf[voff[0] + ro]);
      half8v v1 = __builtin_bit_cast(half8v, *(short8v*)&vbuf[voff[1] + ro]);
      half8v v2 = __builtin_bit_cast(half8v, *(short8v*)&vbuf[voff[2] + ro]);
      half8v v3 = __builtin_bit_cast(half8v, *(short8v*)&vbuf[voff[3] + ro]);
      oacc[t] = __builtin_amdgcn_mfma_f32_32x32x16_f16(v0, pfA0, oacc[t], 0, 0, 0);
      oacc[t] = __builtin_amdgcn_mfma_f32_32x32x16_f16(v1, pfA1, oacc[t], 0, 0, 0);
      oacc[t] = __builtin_amdgcn_mfma_f32_32x32x16_f16(v2, pfB0, oacc[t], 0, 0, 0);
      oacc[t] = __builtin_amdgcn_mfma_f32_32x32x16_f16(v3, pfB1, oacc[t], 0, 0, 0);
    }
    __builtin_amdgcn_s_setprio(0);

    __syncthreads();
    cur ^= 1;
  }

  // ---- epilogue: kh=0 -> fp16 ah; kh=1 -> fp32 yb; side[kh] = l ----
  const float invl = 1.f / lrun;
  const int row = bh * Tt + tq;
  if (hb == 0) side[kh * 65536 + row] = lrun;
  const int bI = bh >> 4, hd = bh & 15;
  if (kh == 0) {
    short* op = ah + ((size_t)(bI * Tt + tq)) * Cc + hd * Dd;
#pragma unroll
    for (int t = 0; t < 2; ++t)
#pragma unroll
      for (int rq = 0; rq < 4; ++rq) {
        short4v hv;
#pragma unroll
        for (int rr = 0; rr < 4; ++rr) hv[rr] = f2h(oacc[t][4 * rq + rr] * invl);
        *(short4v*)(op + 32 * t + 8 * rq + 4 * hb) = hv;
      }
  } else {
    float* yp = yb + (size_t)row * 64;
#pragma unroll
    for (int t = 0; t < 2; ++t)
#pragma unroll
      for (int rq = 0; rq < 4; ++rq) {
        f32x4 o4;
#pragma unroll
        for (int rr = 0; rr < 4; ++rr) o4[rr] = oacc[t][4 * rq + rr] * invl;
        *(f32x4*)(yp + 32 * t + 8 * rq + 4 * hb) = o4;
      }
  }
}

// ---------------- merge the two key-halves (all rows) ----------------
__global__ __launch_bounds__(256) void attn_merge(short* __restrict__ ah,
                                                  const float* __restrict__ yb,
                                                  const float* __restrict__ side) {
  const int bh = blockIdx.y;                         // 0..31
  const int idx = blockIdx.x * 256 + threadIdx.x;    // [0, 8192)
  const int tq = idx >> 2;                           // [0, 2048)
  const int qd = (idx & 3) << 4;
  const int row = bh * Tt + tq;
  const float l0 = side[row], l1 = side[65536 + row];
  const float inv = 1.f / (l0 + l1);
  const float a0 = l0 * inv, a1 = l1 * inv;

  const int bI = bh >> 4, hd = bh & 15;
  short* op = ah + ((size_t)(bI * Tt + tq)) * Cc + hd * Dd + qd;
  const float* yp = yb + (size_t)row * 64 + qd;

  short8v h0 = *(short8v*)op, h1 = *(short8v*)(op + 8);
  short8v o0, o1;
#pragma unroll
  for (int e = 0; e < 8; ++e) o0[e] = f2h(a0 * h2f(h0[e]) + a1 * yp[e]);
#pragma unroll
  for (int e = 0; e < 8; ++e) o1[e] = f2h(a0 * h2f(h1[e]) + a1 * yp[8 + e]);
  *(short8v*)op = o0;
  *(short8v*)(op + 8) = o1;
}

extern "C" void kernel_launch(void* const* d_in, const int* in_sizes, int n_in,
                              void* d_out, int out_size, void* d_ws, size_t ws_size,
                              hipStream_t stream) {
  const float* x  = (const float*)d_in[0];
  const float* Wq = (const float*)d_in[1];
  const float* bq = (const float*)d_in[2];
  const float* Wk = (const float*)d_in[3];
  const float* bk = (const float*)d_in[4];
  const float* Wv = (const float*)d_in[5];
  const float* bv = (const float*)d_in[6];
  const float* Wo = (const float*)d_in[7];
  const float* bo = (const float*)d_in[8];

  short* ws16 = (short*)d_ws;
  short* xh  = ws16;                  // 8MB fp16 x
  short* WTh = ws16 + 4194304;        // 8MB: Wq,Wk,Wv,Wo transposed fp16
  short* qb  = ws16 + 8388608;        // 8MB fp16 [B,H,T,D]
  short* kb  = ws16 + 12582912;       // 8MB fp16 [B,H,T,D]
  short* vb  = ws16 + 16777216;       // 8MB fp16 [B,H,D,T] (V transposed)
  short* ah  = ws16 + 20971520;       // 8MB fp16 attn out [B,T,C]
  float* yb   = (float*)(ws16 + 25165824);  // 16.78MB fp32 kh=1 partials [65536][64]
  float* side = yb + 4194304;               // 0.5MB: [kh][65536] = l
  float* rt   = side + 131072;              // 0.5MB rope table [2048][32] float2

  prep<<<3328, 256, 0, stream>>>(x, Wq, Wk, Wv, Wo, xh, WTh, rt);

  gemm_qkv<<<dim3(256, 3), 256, 0, stream>>>(xh, WTh, bq, bk, bv, rt, qb, kb, vb);

  attn_mfma<<<1024, 256, 0, stream>>>(qb, kb, vb, ah, yb, side);
  attn_merge<<<dim3(32, 32), 256, 0, stream>>>(ah, yb, side);

  gemm_out<<<256, 256, 0, stream>>>(ah, WTh + 3 * 1048576, bo, (float*)d_out);
}

// Round 19
// 111.781 us; speedup vs baseline: 1.3763x; 1.0229x over previous
//
#include <hip/hip_runtime.h>
#include <hip/hip_bf16.h>
#include <math.h>

#define Bsz 2
#define Tt  2048
#define Cc  1024
#define Hh  16
#define Dd  64

typedef __attribute__((ext_vector_type(8))) short short8v;
typedef __attribute__((ext_vector_type(4))) short short4v;
typedef __attribute__((ext_vector_type(8))) _Float16 half8v;
typedef __attribute__((ext_vector_type(4))) float f32x4;
typedef __attribute__((ext_vector_type(16))) float f32x16;
typedef __attribute__((ext_vector_type(4))) unsigned int uint4v;

static __device__ __forceinline__ short f2h(float f) {
  _Float16 h = (_Float16)f;   // v_cvt_f16_f32 (RNE)
  return __builtin_bit_cast(short, h);
}
static __device__ __forceinline__ float h2f(short s) {
  _Float16 h = __builtin_bit_cast(_Float16, s);
  return (float)h;
}
static __device__ __forceinline__ void gll16(const void* g, void* l) {
  __builtin_amdgcn_global_load_lds((const __attribute__((address_space(1))) unsigned int*)g,
                                   (__attribute__((address_space(3))) unsigned int*)l, 16, 0, 0);
}

// ---------------- fused prepass: cast x, cast+transpose W, rope table ----------------
__global__ __launch_bounds__(256) void prep(const float* __restrict__ x,
                                            const float* __restrict__ Wq,
                                            const float* __restrict__ Wk,
                                            const float* __restrict__ Wv,
                                            const float* __restrict__ Wo,
                                            short* __restrict__ xh,
                                            short* __restrict__ WTh,
                                            float* __restrict__ rt) {
  __shared__ float T[64][68];
  const int bid = blockIdx.x;
  const int tid = threadIdx.x;

  if (bid < 2048) {           // ---- cast x ----
    int t = bid * 256 + tid;
    const float* s = x + (size_t)t * 8;
    float4 a = *(const float4*)s, b = *(const float4*)(s + 4);
    short8v h;
    h[0] = f2h(a.x); h[1] = f2h(a.y); h[2] = f2h(a.z); h[3] = f2h(a.w);
    h[4] = f2h(b.x); h[5] = f2h(b.y); h[6] = f2h(b.z); h[7] = f2h(b.w);
    *(short8v*)(xh + (size_t)t * 8) = h;
  } else if (bid < 3072) {    // ---- cast + transpose W ----
    const int z = (bid - 2048) >> 8;
    const int slot = (bid - 2048) & 255;
    const float* W = z == 0 ? Wq : z == 1 ? Wk : z == 2 ? Wv : Wo;
    short* oh = WTh + (size_t)z * 1048576;
    const int n0 = (slot & 15) * 64, k0 = (slot >> 4) * 64;
#pragma unroll
    for (int i = 0; i < 4; ++i) {
      int s2 = tid + i * 256;
      int r = s2 >> 4, c4 = (s2 & 15) << 2;
      *(float4*)&T[r][c4] = *(const float4*)(W + (size_t)(k0 + r) * Cc + n0 + c4);
    }
    __syncthreads();
#pragma unroll
    for (int i = 0; i < 2; ++i) {
      int s2 = tid + i * 256;
      int nl = s2 >> 3, ks = (s2 & 7) << 3;
      short8v h;
#pragma unroll
      for (int e = 0; e < 8; ++e) h[e] = f2h(T[ks + e][nl]);
      *(short8v*)(oh + (size_t)(n0 + nl) * Cc + k0 + ks) = h;
    }
  } else {                    // ---- rope table ----
    int idx = (bid - 3072) * 256 + tid;   // [0, 65536)
    int t = idx >> 5, p = idx & 31;
    float inv = exp2f(-(float)p * (13.2877123795494f / 32.f));
    float sn, cs;
    sincosf((float)t * inv, &sn, &cs);
    float2 v; v.x = cs; v.y = sn;
    *(float2*)(rt + (size_t)idx * 2) = v;
  }
}

// ================= 128x128 fp16 GEMM core, BK=64 (for gemm_qkv) =================
__device__ __forceinline__ void core128h(const short* __restrict__ Ah,
                                         const short* __restrict__ Bh,
                                         short* AhL, short* BhL,
                                         int row0, int col0, int wv, int lane, f32x4 acc[4][4]) {
  const int l15 = lane & 15, g = lane >> 4;
  const int wr = wv >> 1, wc = wv & 1;

  const int r8 = lane >> 3;
  const int sch = ((lane & 7) ^ r8) << 3;
  size_t aoff[4], boff[4];
#pragma unroll
  for (int gi = 0; gi < 4; ++gi) {
    aoff[gi] = (size_t)(row0 + wv * 32 + 8 * gi + r8) * Cc + sch;
    boff[gi] = (size_t)(col0 + wv * 32 + 8 * gi + r8) * Cc + sch;
  }
  short* dA = AhL + wv * 2048;
  short* dB = BhL + wv * 2048;

  int aL[4][2], bL[4][2];
#pragma unroll
  for (int m = 0; m < 4; ++m)
#pragma unroll
    for (int s = 0; s < 2; ++s) {
      aL[m][s] = (wr * 64 + m * 16 + l15) * 64 + (((4 * s + g) ^ (l15 & 7)) << 3);
      bL[m][s] = (wc * 64 + m * 16 + l15) * 64 + (((4 * s + g) ^ (l15 & 7)) << 3);
    }

  for (int k0 = 0; k0 < Cc; k0 += 64) {
    __syncthreads();
#pragma unroll
    for (int gi = 0; gi < 4; ++gi) {
      gll16(Ah + aoff[gi] + k0, dA + gi * 512);
      gll16(Bh + boff[gi] + k0, dB + gi * 512);
    }
    __syncthreads();
#pragma unroll
    for (int s = 0; s < 2; ++s) {
      half8v a[4], b[4];
#pragma unroll
      for (int m = 0; m < 4; ++m) a[m] = __builtin_bit_cast(half8v, *(short8v*)&AhL[aL[m][s]]);
#pragma unroll
      for (int n = 0; n < 4; ++n) b[n] = __builtin_bit_cast(half8v, *(short8v*)&BhL[bL[n][s]]);
#pragma unroll
      for (int m = 0; m < 4; ++m)
#pragma unroll
        for (int n = 0; n < 4; ++n)
          acc[m][n] = __builtin_amdgcn_mfma_f32_16x16x32_f16(a[m], b[n], acc[m][n], 0, 0, 0);
    }
  }
}

// ---------------- QKV projection GEMM (fp16), rope via table, V transposed ----------------
__global__ __launch_bounds__(256, 3) void gemm_qkv(const short* __restrict__ xh,
                                                   const short* __restrict__ WTh,
                                                   const float* __restrict__ bq,
                                                   const float* __restrict__ bk,
                                                   const float* __restrict__ bv,
                                                   const float* __restrict__ rt,
                                                   short* __restrict__ qb,
                                                   short* __restrict__ kb,
                                                   short* __restrict__ vb) {
  __shared__ short AhL[8192], BhL[8192];
  const int mode = blockIdx.y;
  const short* Bh = WTh + (size_t)mode * 1048576;
  const float* bias = mode == 0 ? bq : mode == 1 ? bk : bv;
  short* Y = mode == 0 ? qb : mode == 1 ? kb : vb;

  const int bid = blockIdx.x;
  const int nid = ((bid & 7) << 5) | (bid >> 3);
  const int row0 = (nid >> 3) * 128, col0 = (nid & 7) * 128;
  const int lane = threadIdx.x & 63, wv = threadIdx.x >> 6;
  const int l15 = lane & 15, g = lane >> 4;
  const int wr = wv >> 1, wc = wv & 1;

  f32x4 acc[4][4];
#pragma unroll
  for (int m = 0; m < 4; ++m)
#pragma unroll
    for (int n = 0; n < 4; ++n) acc[m][n] = (f32x4){0.f, 0.f, 0.f, 0.f};

  core128h(xh, Bh, AhL, BhL, row0, col0, wv, lane, acc);

  const int cbase = col0 + wc * 64;
  const int h = cbase >> 6;
  if (mode < 2) {
    const float scale = (mode == 0) ? 0.18033688f : 1.0f;   // 1/8 * log2(e) folded for Q
    const float2* rt2 = (const float2*)rt;
#pragma unroll
    for (int n = 0; n < 2; ++n) {
      const int d = n * 16 + l15;
      const float b0 = bias[cbase + d], b1 = bias[cbase + d + 32];
#pragma unroll
      for (int m = 0; m < 4; ++m)
#pragma unroll
        for (int rr = 0; rr < 4; ++rr) {
          int R = row0 + wr * 64 + m * 16 + g * 4 + rr;
          int bI = R >> 11, t = R & (Tt - 1);
          float2 cssn = rt2[t * 32 + d];
          float v0 = acc[m][n][rr] + b0, v1 = acc[m][n + 2][rr] + b1;
          size_t base = (((size_t)(bI * Hh + h) * Tt + t) << 6) + d;
          Y[base]      = f2h((v0 * cssn.x - v1 * cssn.y) * scale);
          Y[base + 32] = f2h((v1 * cssn.x + v0 * cssn.y) * scale);
        }
    }
  } else {
    // V: write transposed [B,H,D,T] fp16
#pragma unroll
    for (int n = 0; n < 2; ++n) {
      const int d = n * 16 + l15;
      const float b0 = bias[cbase + d], b1 = bias[cbase + d + 32];
#pragma unroll
      for (int m = 0; m < 4; ++m) {
        int R = row0 + wr * 64 + m * 16 + g * 4;
        int bI = R >> 11, t = R & (Tt - 1);
        short4v s0, s1;
#pragma unroll
        for (int rr = 0; rr < 4; ++rr) {
          s0[rr] = f2h(acc[m][n][rr] + b0);
          s1[rr] = f2h(acc[m][n + 2][rr] + b1);
        }
        size_t base = ((size_t)(bI * Hh + h) * Dd);
        *(short4v*)(Y + (base + d) * Tt + t)      = s0;
        *(short4v*)(Y + (base + d + 32) * Tt + t) = s1;
      }
    }
  }
}

// ---------------- final output GEMM: 128x64 tiles, 512 blocks (2/CU) ----------------
// 4 waves stacked on M (wave tile 32x64, acc[2][4]); BK=64; LDS A 16KB + B 8KB.
__global__ __launch_bounds__(256, 4) void gemm_out(const short* __restrict__ ah,
                                                   const short* __restrict__ WTo,
                                                   const float* __restrict__ bias,
                                                   float* __restrict__ Y) {
  __shared__ short AhL[8192], BhL[4096];
  const int bid = blockIdx.x;                      // 512
  const int nid = ((bid & 7) << 6) | (bid >> 3);   // XCD swizzle, bijective
  const int row0 = (nid >> 4) * 128, col0 = (nid & 15) * 64;
  const int lane = threadIdx.x & 63, wv = threadIdx.x >> 6;
  const int l15 = lane & 15, g = lane >> 4;

  const int r8 = lane >> 3;
  const int sch = ((lane & 7) ^ r8) << 3;
  size_t aoff[4], boff[2];
#pragma unroll
  for (int gi = 0; gi < 4; ++gi)
    aoff[gi] = (size_t)(row0 + wv * 32 + 8 * gi + r8) * Cc + sch;
#pragma unroll
  for (int gi = 0; gi < 2; ++gi)
    boff[gi] = (size_t)(col0 + wv * 16 + 8 * gi + r8) * Cc + sch;
  short* dA = AhL + wv * 2048;
  short* dB = BhL + wv * 1024;

  int aL[2][2], bL[4][2];
#pragma unroll
  for (int m = 0; m < 2; ++m)
#pragma unroll
    for (int s = 0; s < 2; ++s)
      aL[m][s] = (wv * 32 + m * 16 + l15) * 64 + (((4 * s + g) ^ (l15 & 7)) << 3);
#pragma unroll
  for (int n = 0; n < 4; ++n)
#pragma unroll
    for (int s = 0; s < 2; ++s)
      bL[n][s] = (n * 16 + l15) * 64 + (((4 * s + g) ^ (l15 & 7)) << 3);

  f32x4 acc[2][4];
#pragma unroll
  for (int m = 0; m < 2; ++m)
#pragma unroll
    for (int n = 0; n < 4; ++n) acc[m][n] = (f32x4){0.f, 0.f, 0.f, 0.f};

  for (int k0 = 0; k0 < Cc; k0 += 64) {
    __syncthreads();
#pragma unroll
    for (int gi = 0; gi < 4; ++gi) gll16(ah + aoff[gi] + k0, dA + gi * 512);
#pragma unroll
    for (int gi = 0; gi < 2; ++gi) gll16(WTo + boff[gi] + k0, dB + gi * 512);
    __syncthreads();
#pragma unroll
    for (int s = 0; s < 2; ++s) {
      half8v a[2], b[4];
#pragma unroll
      for (int m = 0; m < 2; ++m) a[m] = __builtin_bit_cast(half8v, *(short8v*)&AhL[aL[m][s]]);
#pragma unroll
      for (int n = 0; n < 4; ++n) b[n] = __builtin_bit_cast(half8v, *(short8v*)&BhL[bL[n][s]]);
#pragma unroll
      for (int m = 0; m < 2; ++m)
#pragma unroll
        for (int n = 0; n < 4; ++n)
          acc[m][n] = __builtin_amdgcn_mfma_f32_16x16x32_f16(a[m], b[n], acc[m][n], 0, 0, 0);
    }
  }

#pragma unroll
  for (int n = 0; n < 4; ++n) {
    const int ccol = col0 + n * 16 + l15;
    const float b0 = bias[ccol];
#pragma unroll
    for (int m = 0; m < 2; ++m)
#pragma unroll
      for (int rr = 0; rr < 4; ++rr) {
        int R = row0 + wv * 32 + m * 16 + g * 4 + rr;
        Y[(size_t)R * Cc + ccol] = acc[m][n][rr] + b0;
      }
  }
}

// ================= MFMA flash attention: split-K=3 =================
// 48 jobs/bh (each q-tile's key range in thirds), grid 1536 (~5-6 blocks/CU,
// LDS-capped 5; excess blocks queue -> dynamic load balancing).
// kh=0 -> ah (strided fp16); kh=1/2 -> dense fp16 partials p1/p2; side[kh]=l.
static __device__ const int JQ3[48] = {0,0,0, 1,1,1, 2,2,2, 3,3,3, 4,4,4, 5,5,5,
                                       6,6,6, 7,7,7, 8,8,8, 9,9,9, 10,10,10,
                                       11,11,11, 12,12,12, 13,13,13, 14,14,14,
                                       15,15,15};
static __device__ const int JK3[48] = {0,1,2, 0,1,2, 0,1,2, 0,1,2, 0,1,2, 0,1,2,
                                       0,1,2, 0,1,2, 0,1,2, 0,1,2, 0,1,2, 0,1,2,
                                       0,1,2, 0,1,2, 0,1,2, 0,1,2};

__global__ __launch_bounds__(256, 4) void attn_mfma(const short* __restrict__ q,
                                                    const short* __restrict__ k,
                                                    const short* __restrict__ vT,
                                                    short* __restrict__ ah,
                                                    short* __restrict__ p1,
                                                    short* __restrict__ p2,
                                                    float* __restrict__ side) {
  const int n = blockIdx.x;           // 1536
  const int xcd = n & 7;
  const int t7 = n >> 3;              // 0..191
  const int bhj = t7 & 3;
  const int j = t7 >> 2;              // 0..47
  const int bh = xcd * 4 + bhj;
  const int Q = JQ3[j];
  const int kh = JK3[j];
  const int q0 = Q * 128;

  const int tid = threadIdx.x;
  const int lane = tid & 63;
  const int wv = tid >> 6;
  const int l31 = lane & 31;
  const int hb = lane >> 5;
  const int qbase = q0 + wv * 32;
  const int tq = qbase + l31;

  const short* qgb = q + (size_t)bh * Tt * Dd;
  const short* kgb = k + (size_t)bh * Tt * Dd;
  const short* vgb = vT + (size_t)bh * Dd * Tt;

  const short* qp = qgb + (size_t)tq * Dd + 8 * hb;
  half8v qf[4];
#pragma unroll
  for (int i = 0; i < 4; ++i) qf[i] = __builtin_bit_cast(half8v, *(const short8v*)(qp + 16 * i));

  __shared__ short Klds[2][4096];
  __shared__ short Vt[2][4096];

  const int r8 = lane >> 3;
  const size_t ksrc0 = (size_t)(wv * 16 + r8) * Dd + (((lane & 7) ^ r8) << 3);
  const size_t ksrc1 = ksrc0 + (size_t)8 * Dd;
  const int vlog = ((lane & 7) - r8) & 7;
  const size_t vsrc0 = (size_t)(wv * 16 + r8) * Tt + (vlog << 3);
  const size_t vsrc1 = vsrc0 + (size_t)8 * Tt;

#define STAGE64(BUF, JT)                                                     \
  {                                                                          \
    gll16(kgb + (size_t)(JT) * Dd + ksrc0, &Klds[BUF][wv * 1024]);           \
    gll16(kgb + (size_t)(JT) * Dd + ksrc1, &Klds[BUF][wv * 1024 + 512]);     \
    gll16(vgb + vsrc0 + (JT), &Vt[BUF][wv * 1024]);                          \
    gll16(vgb + vsrc1 + (JT), &Vt[BUF][wv * 1024 + 512]);                    \
  }

  int koff[4], voff[4];
#pragma unroll
  for (int i = 0; i < 4; ++i) {
    koff[i] = l31 * 64 + (((2 * i + hb) ^ (l31 & 7)) << 3);
    voff[i] = l31 * 64 + ((((2 * i + hb) + (l31 & 7)) & 7) << 3);
  }

  f32x16 oacc[2];
#pragma unroll
  for (int t = 0; t < 2; ++t)
#pragma unroll
    for (int r = 0; r < 16; ++r) oacc[t][r] = 0.f;
  float lrun = 0.f;

  const int cs0 = (q0 >= 512) ? (q0 - 511) : 0;
  const int cstart = cs0 & ~63;
  const int nch_b = (Tt - cstart) >> 6;
  const int start_i = (nch_b * kh) / 3;
  const int end_i = (nch_b * (kh + 1)) / 3;
  const int mystart = cstart + (start_i << 6);
  const int myn = end_i - start_i;

  STAGE64(0, mystart);
  __syncthreads();

  int cur = 0;
  for (int ci = 0; ci < myn; ++ci) {
    const int jt = mystart + (ci << 6);

    if (ci + 1 < myn) STAGE64(cur ^ 1, jt + 64);

    const short* kbuf = &Klds[cur][0];
    f32x16 seA, seB;
#pragma unroll
    for (int r = 0; r < 16; ++r) { seA[r] = 0.f; seB[r] = 0.f; }
    __builtin_amdgcn_s_setprio(1);
#pragma unroll
    for (int i = 0; i < 4; ++i) {
      half8v kfA = __builtin_bit_cast(half8v, *(short8v*)&kbuf[koff[i]]);
      seA = __builtin_amdgcn_mfma_f32_32x32x16_f16(kfA, qf[i], seA, 0, 0, 0);
    }
#pragma unroll
    for (int i = 0; i < 4; ++i) {
      half8v kfB = __builtin_bit_cast(half8v, *(short8v*)&kbuf[koff[i] + 2048]);
      seB = __builtin_amdgcn_mfma_f32_32x32x16_f16(kfB, qf[i], seB, 0, 0, 0);
    }
    __builtin_amdgcn_s_setprio(0);

    if (jt < qbase - 480) {
      int th = tq - 511 - jt;
#pragma unroll
      for (int r = 0; r < 16; ++r) {
        int row = (r & 3) + 8 * (r >> 2) + 4 * hb;
        if (row < th) seA[r] = -1e30f;
        if (32 + row < th) seB[r] = -1e30f;
      }
    }

    float pA[16], pB[16];
#pragma unroll
    for (int r = 0; r < 16; ++r) {
      asm("v_exp_f32 %0, %1" : "=v"(pA[r]) : "v"(seA[r]));
      asm("v_exp_f32 %0, %1" : "=v"(pB[r]) : "v"(seB[r]));
    }
    float t0 = 0.f, t1 = 0.f, t2 = 0.f, t3 = 0.f;
#pragma unroll
    for (int r = 0; r < 16; r += 4) {
      t0 += pA[r];     t1 += pA[r + 1]; t2 += pA[r + 2]; t3 += pA[r + 3];
      t0 += pB[r];     t1 += pB[r + 1]; t2 += pB[r + 2]; t3 += pB[r + 3];
    }
    float psum = (t0 + t1) + (t2 + t3);
    psum += __shfl_xor(psum, 32);
    lrun += psum;

    unsigned pa[8], pb[8];
#pragma unroll
    for (int i = 0; i < 8; ++i) {
      pa[i] = __builtin_bit_cast(unsigned, __builtin_amdgcn_cvt_pkrtz(pA[2 * i], pA[2 * i + 1]));
      pb[i] = __builtin_bit_cast(unsigned, __builtin_amdgcn_cvt_pkrtz(pB[2 * i], pB[2 * i + 1]));
    }
    asm volatile("v_permlane32_swap_b32 %0, %1" : "+v"(pa[0]), "+v"(pa[2]));
    asm volatile("v_permlane32_swap_b32 %0, %1" : "+v"(pa[1]), "+v"(pa[3]));
    asm volatile("v_permlane32_swap_b32 %0, %1" : "+v"(pa[4]), "+v"(pa[6]));
    asm volatile("v_permlane32_swap_b32 %0, %1" : "+v"(pa[5]), "+v"(pa[7]));
    asm volatile("v_permlane32_swap_b32 %0, %1" : "+v"(pb[0]), "+v"(pb[2]));
    asm volatile("v_permlane32_swap_b32 %0, %1" : "+v"(pb[1]), "+v"(pb[3]));
    asm volatile("v_permlane32_swap_b32 %0, %1" : "+v"(pb[4]), "+v"(pb[6]));
    asm volatile("v_permlane32_swap_b32 %0, %1" : "+v"(pb[5]), "+v"(pb[7]));
    uint4v fA0, fA1, fB0, fB1;
    fA0[0] = pa[0]; fA0[1] = pa[1]; fA0[2] = pa[2]; fA0[3] = pa[3];
    fA1[0] = pa[4]; fA1[1] = pa[5]; fA1[2] = pa[6]; fA1[3] = pa[7];
    fB0[0] = pb[0]; fB0[1] = pb[1]; fB0[2] = pb[2]; fB0[3] = pb[3];
    fB1[0] = pb[4]; fB1[1] = pb[5]; fB1[2] = pb[6]; fB1[3] = pb[7];
    half8v pfA0 = __builtin_bit_cast(half8v, fA0);
    half8v pfA1 = __builtin_bit_cast(half8v, fA1);
    half8v pfB0 = __builtin_bit_cast(half8v, fB0);
    half8v pfB1 = __builtin_bit_cast(half8v, fB1);

    const short* vbuf = &Vt[cur][0];
    __builtin_amdgcn_s_setprio(1);
#pragma unroll
    for (int t = 0; t < 2; ++t) {
      const int ro = t * 2048;
      half8v v0 = __builtin_bit_cast(half8v, *(short8v*)&vbuf[voff[0] + ro]);
      half8v v1 = __builtin_bit_cast(half8v, *(short8v*)&vbuf[voff[1] + ro]);
      half8v v2 = __builtin_bit_cast(half8v, *(short8v*)&vbuf[voff[2] + ro]);
      half8v v3 = __builtin_bit_cast(half8v, *(short8v*)&vbuf[voff[3] + ro]);
      oacc[t] = __builtin_amdgcn_mfma_f32_32x32x16_f16(v0, pfA0, oacc[t], 0, 0, 0);
      oacc[t] = __builtin_amdgcn_mfma_f32_32x32x16_f16(v1, pfA1, oacc[t], 0, 0, 0);
      oacc[t] = __builtin_amdgcn_mfma_f32_32x32x16_f16(v2, pfB0, oacc[t], 0, 0, 0);
      oacc[t] = __builtin_amdgcn_mfma_f32_32x32x16_f16(v3, pfB1, oacc[t], 0, 0, 0);
    }
    __builtin_amdgcn_s_setprio(0);

    __syncthreads();
    cur ^= 1;
  }

  // ---- epilogue: kh=0 -> ah strided; kh=1/2 -> dense fp16 partial ----
  const float invl = 1.f / lrun;
  const int row = bh * Tt + tq;
  if (hb == 0) side[kh * 65536 + row] = lrun;
  const int bI = bh >> 4, hd = bh & 15;
  if (kh == 0) {
    short* op = ah + ((size_t)(bI * Tt + tq)) * Cc + hd * Dd;
#pragma unroll
    for (int t = 0; t < 2; ++t)
#pragma unroll
      for (int rq = 0; rq < 4; ++rq) {
        short4v hv;
#pragma unroll
        for (int rr = 0; rr < 4; ++rr) hv[rr] = f2h(oacc[t][4 * rq + rr] * invl);
        *(short4v*)(op + 32 * t + 8 * rq + 4 * hb) = hv;
      }
  } else {
    short* pp = (kh == 1 ? p1 : p2) + (size_t)row * 64;
#pragma unroll
    for (int t = 0; t < 2; ++t)
#pragma unroll
      for (int rq = 0; rq < 4; ++rq) {
        short4v hv;
#pragma unroll
        for (int rr = 0; rr < 4; ++rr) hv[rr] = f2h(oacc[t][4 * rq + rr] * invl);
        *(short4v*)(pp + 32 * t + 8 * rq + 4 * hb) = hv;
      }
  }
}

// ---------------- merge the three key-thirds (all rows) ----------------
__global__ __launch_bounds__(256) void attn_merge(short* __restrict__ ah,
                                                  const short* __restrict__ p1,
                                                  const short* __restrict__ p2,
                                                  const float* __restrict__ side) {
  const int bh = blockIdx.y;                         // 0..31
  const int idx = blockIdx.x * 256 + threadIdx.x;    // [0, 8192)
  const int tq = idx >> 2;                           // [0, 2048)
  const int qd = (idx & 3) << 4;
  const int row = bh * Tt + tq;
  const float l0 = side[row], l1 = side[65536 + row], l2 = side[131072 + row];
  const float inv = 1.f / (l0 + l1 + l2);
  const float a0 = l0 * inv, a1 = l1 * inv, a2 = l2 * inv;

  const int bI = bh >> 4, hd = bh & 15;
  short* op = ah + ((size_t)(bI * Tt + tq)) * Cc + hd * Dd + qd;
  const short* r1 = p1 + (size_t)row * 64 + qd;
  const short* r2 = p2 + (size_t)row * 64 + qd;

  short8v h0 = *(short8v*)op,        h1 = *(short8v*)(op + 8);
  short8v u0 = *(const short8v*)r1,  u1 = *(const short8v*)(r1 + 8);
  short8v w0 = *(const short8v*)r2,  w1 = *(const short8v*)(r2 + 8);
  short8v o0, o1;
#pragma unroll
  for (int e = 0; e < 8; ++e)
    o0[e] = f2h(a0 * h2f(h0[e]) + a1 * h2f(u0[e]) + a2 * h2f(w0[e]));
#pragma unroll
  for (int e = 0; e < 8; ++e)
    o1[e] = f2h(a0 * h2f(h1[e]) + a1 * h2f(u1[e]) + a2 * h2f(w1[e]));
  *(short8v*)op = o0;
  *(short8v*)(op + 8) = o1;
}

extern "C" void kernel_launch(void* const* d_in, const int* in_sizes, int n_in,
                              void* d_out, int out_size, void* d_ws, size_t ws_size,
                              hipStream_t stream) {
  const float* x  = (const float*)d_in[0];
  const float* Wq = (const float*)d_in[1];
  const float* bq = (const float*)d_in[2];
  const float* Wk = (const float*)d_in[3];
  const float* bk = (const float*)d_in[4];
  const float* Wv = (const float*)d_in[5];
  const float* bv = (const float*)d_in[6];
  const float* Wo = (const float*)d_in[7];
  const float* bo = (const float*)d_in[8];

  short* ws16 = (short*)d_ws;
  short* xh  = ws16;                  // 8MB fp16 x
  short* WTh = ws16 + 4194304;        // 8MB: Wq,Wk,Wv,Wo transposed fp16
  short* qb  = ws16 + 8388608;        // 8MB fp16 [B,H,T,D]
  short* kb  = ws16 + 12582912;       // 8MB fp16 [B,H,T,D]
  short* vb  = ws16 + 16777216;       // 8MB fp16 [B,H,D,T] (V transposed)
  short* ah  = ws16 + 20971520;       // 8MB fp16 attn out [B,T,C]
  short* p1  = ws16 + 25165824;       // 8MB fp16 kh=1 partial [65536][64]
  short* p2  = ws16 + 29360128;       // 8MB fp16 kh=2 partial
  float* side = (float*)(ws16 + 33554432); // 0.75MB: [kh][65536] = l
  float* rt   = side + 196608;             // 0.5MB rope table [2048][32] float2

  prep<<<3328, 256, 0, stream>>>(x, Wq, Wk, Wv, Wo, xh, WTh, rt);

  gemm_qkv<<<dim3(256, 3), 256, 0, stream>>>(xh, WTh, bq, bk, bv, rt, qb, kb, vb);

  attn_mfma<<<1536, 256, 0, stream>>>(qb, kb, vb, ah, p1, p2, side);
  attn_merge<<<dim3(32, 32), 256, 0, stream>>>(ah, p1, p2, side);

  gemm_out<<<512, 256, 0, stream>>>(ah, WTh + 3 * 1048576, bo, (float*)d_out);
}

// Round 20
// 109.533 us; speedup vs baseline: 1.4046x; 1.0205x over previous
//
#include <hip/hip_runtime.h>
#include <hip/hip_bf16.h>
#include <math.h>

#define Bsz 2
#define Tt  2048
#define Cc  1024
#define Hh  16
#define Dd  64

typedef __attribute__((ext_vector_type(8))) short short8v;
typedef __attribute__((ext_vector_type(4))) short short4v;
typedef __attribute__((ext_vector_type(8))) _Float16 half8v;
typedef __attribute__((ext_vector_type(4))) float f32x4;
typedef __attribute__((ext_vector_type(16))) float f32x16;
typedef __attribute__((ext_vector_type(4))) unsigned int uint4v;

static __device__ __forceinline__ short f2h(float f) {
  _Float16 h = (_Float16)f;   // v_cvt_f16_f32 (RNE)
  return __builtin_bit_cast(short, h);
}
static __device__ __forceinline__ float h2f(short s) {
  _Float16 h = __builtin_bit_cast(_Float16, s);
  return (float)h;
}
static __device__ __forceinline__ void gll16(const void* g, void* l) {
  __builtin_amdgcn_global_load_lds((const __attribute__((address_space(1))) unsigned int*)g,
                                   (__attribute__((address_space(3))) unsigned int*)l, 16, 0, 0);
}

// ---------------- fused prepass: cast x, cast+transpose W, rope table ----------------
__global__ __launch_bounds__(256) void prep(const float* __restrict__ x,
                                            const float* __restrict__ Wq,
                                            const float* __restrict__ Wk,
                                            const float* __restrict__ Wv,
                                            const float* __restrict__ Wo,
                                            short* __restrict__ xh,
                                            short* __restrict__ WTh,
                                            float* __restrict__ rt) {
  __shared__ float T[64][68];
  const int bid = blockIdx.x;
  const int tid = threadIdx.x;

  if (bid < 2048) {           // ---- cast x ----
    int t = bid * 256 + tid;
    const float* s = x + (size_t)t * 8;
    float4 a = *(const float4*)s, b = *(const float4*)(s + 4);
    short8v h;
    h[0] = f2h(a.x); h[1] = f2h(a.y); h[2] = f2h(a.z); h[3] = f2h(a.w);
    h[4] = f2h(b.x); h[5] = f2h(b.y); h[6] = f2h(b.z); h[7] = f2h(b.w);
    *(short8v*)(xh + (size_t)t * 8) = h;
  } else if (bid < 3072) {    // ---- cast + transpose W ----
    const int z = (bid - 2048) >> 8;
    const int slot = (bid - 2048) & 255;
    const float* W = z == 0 ? Wq : z == 1 ? Wk : z == 2 ? Wv : Wo;
    short* oh = WTh + (size_t)z * 1048576;
    const int n0 = (slot & 15) * 64, k0 = (slot >> 4) * 64;
#pragma unroll
    for (int i = 0; i < 4; ++i) {
      int s2 = tid + i * 256;
      int r = s2 >> 4, c4 = (s2 & 15) << 2;
      *(float4*)&T[r][c4] = *(const float4*)(W + (size_t)(k0 + r) * Cc + n0 + c4);
    }
    __syncthreads();
#pragma unroll
    for (int i = 0; i < 2; ++i) {
      int s2 = tid + i * 256;
      int nl = s2 >> 3, ks = (s2 & 7) << 3;
      short8v h;
#pragma unroll
      for (int e = 0; e < 8; ++e) h[e] = f2h(T[ks + e][nl]);
      *(short8v*)(oh + (size_t)(n0 + nl) * Cc + k0 + ks) = h;
    }
  } else {                    // ---- rope table ----
    int idx = (bid - 3072) * 256 + tid;   // [0, 65536)
    int t = idx >> 5, p = idx & 31;
    float inv = exp2f(-(float)p * (13.2877123795494f / 32.f));
    float sn, cs;
    sincosf((float)t * inv, &sn, &cs);
    float2 v; v.x = cs; v.y = sn;
    *(float2*)(rt + (size_t)idx * 2) = v;
  }
}

// ================= 128x128 fp16 GEMM core, BK=64 (for gemm_qkv) =================
__device__ __forceinline__ void core128h(const short* __restrict__ Ah,
                                         const short* __restrict__ Bh,
                                         short* AhL, short* BhL,
                                         int row0, int col0, int wv, int lane, f32x4 acc[4][4]) {
  const int l15 = lane & 15, g = lane >> 4;
  const int wr = wv >> 1, wc = wv & 1;

  const int r8 = lane >> 3;
  const int sch = ((lane & 7) ^ r8) << 3;
  size_t aoff[4], boff[4];
#pragma unroll
  for (int gi = 0; gi < 4; ++gi) {
    aoff[gi] = (size_t)(row0 + wv * 32 + 8 * gi + r8) * Cc + sch;
    boff[gi] = (size_t)(col0 + wv * 32 + 8 * gi + r8) * Cc + sch;
  }
  short* dA = AhL + wv * 2048;
  short* dB = BhL + wv * 2048;

  int aL[4][2], bL[4][2];
#pragma unroll
  for (int m = 0; m < 4; ++m)
#pragma unroll
    for (int s = 0; s < 2; ++s) {
      aL[m][s] = (wr * 64 + m * 16 + l15) * 64 + (((4 * s + g) ^ (l15 & 7)) << 3);
      bL[m][s] = (wc * 64 + m * 16 + l15) * 64 + (((4 * s + g) ^ (l15 & 7)) << 3);
    }

  for (int k0 = 0; k0 < Cc; k0 += 64) {
    __syncthreads();
#pragma unroll
    for (int gi = 0; gi < 4; ++gi) {
      gll16(Ah + aoff[gi] + k0, dA + gi * 512);
      gll16(Bh + boff[gi] + k0, dB + gi * 512);
    }
    __syncthreads();
#pragma unroll
    for (int s = 0; s < 2; ++s) {
      half8v a[4], b[4];
#pragma unroll
      for (int m = 0; m < 4; ++m) a[m] = __builtin_bit_cast(half8v, *(short8v*)&AhL[aL[m][s]]);
#pragma unroll
      for (int n = 0; n < 4; ++n) b[n] = __builtin_bit_cast(half8v, *(short8v*)&BhL[bL[n][s]]);
#pragma unroll
      for (int m = 0; m < 4; ++m)
#pragma unroll
        for (int n = 0; n < 4; ++n)
          acc[m][n] = __builtin_amdgcn_mfma_f32_16x16x32_f16(a[m], b[n], acc[m][n], 0, 0, 0);
    }
  }
}

// ---------------- QKV projection GEMM (fp16), rope via table, V transposed ----------------
__global__ __launch_bounds__(256, 3) void gemm_qkv(const short* __restrict__ xh,
                                                   const short* __restrict__ WTh,
                                                   const float* __restrict__ bq,
                                                   const float* __restrict__ bk,
                                                   const float* __restrict__ bv,
                                                   const float* __restrict__ rt,
                                                   short* __restrict__ qb,
                                                   short* __restrict__ kb,
                                                   short* __restrict__ vb) {
  __shared__ short AhL[8192], BhL[8192];
  const int mode = blockIdx.y;
  const short* Bh = WTh + (size_t)mode * 1048576;
  const float* bias = mode == 0 ? bq : mode == 1 ? bk : bv;
  short* Y = mode == 0 ? qb : mode == 1 ? kb : vb;

  const int bid = blockIdx.x;
  const int nid = ((bid & 7) << 5) | (bid >> 3);
  const int row0 = (nid >> 3) * 128, col0 = (nid & 7) * 128;
  const int lane = threadIdx.x & 63, wv = threadIdx.x >> 6;
  const int l15 = lane & 15, g = lane >> 4;
  const int wr = wv >> 1, wc = wv & 1;

  f32x4 acc[4][4];
#pragma unroll
  for (int m = 0; m < 4; ++m)
#pragma unroll
    for (int n = 0; n < 4; ++n) acc[m][n] = (f32x4){0.f, 0.f, 0.f, 0.f};

  core128h(xh, Bh, AhL, BhL, row0, col0, wv, lane, acc);

  const int cbase = col0 + wc * 64;
  const int h = cbase >> 6;
  if (mode < 2) {
    const float scale = (mode == 0) ? 0.18033688f : 1.0f;   // 1/8 * log2(e) folded for Q
    const float2* rt2 = (const float2*)rt;
#pragma unroll
    for (int n = 0; n < 2; ++n) {
      const int d = n * 16 + l15;
      const float b0 = bias[cbase + d], b1 = bias[cbase + d + 32];
#pragma unroll
      for (int m = 0; m < 4; ++m)
#pragma unroll
        for (int rr = 0; rr < 4; ++rr) {
          int R = row0 + wr * 64 + m * 16 + g * 4 + rr;
          int bI = R >> 11, t = R & (Tt - 1);
          float2 cssn = rt2[t * 32 + d];
          float v0 = acc[m][n][rr] + b0, v1 = acc[m][n + 2][rr] + b1;
          size_t base = (((size_t)(bI * Hh + h) * Tt + t) << 6) + d;
          Y[base]      = f2h((v0 * cssn.x - v1 * cssn.y) * scale);
          Y[base + 32] = f2h((v1 * cssn.x + v0 * cssn.y) * scale);
        }
    }
  } else {
    // V: write transposed [B,H,D,T] fp16
#pragma unroll
    for (int n = 0; n < 2; ++n) {
      const int d = n * 16 + l15;
      const float b0 = bias[cbase + d], b1 = bias[cbase + d + 32];
#pragma unroll
      for (int m = 0; m < 4; ++m) {
        int R = row0 + wr * 64 + m * 16 + g * 4;
        int bI = R >> 11, t = R & (Tt - 1);
        short4v s0, s1;
#pragma unroll
        for (int rr = 0; rr < 4; ++rr) {
          s0[rr] = f2h(acc[m][n][rr] + b0);
          s1[rr] = f2h(acc[m][n + 2][rr] + b1);
        }
        size_t base = ((size_t)(bI * Hh + h) * Dd);
        *(short4v*)(Y + (base + d) * Tt + t)      = s0;
        *(short4v*)(Y + (base + d + 32) * Tt + t) = s1;
      }
    }
  }
}

// ---------------- final output GEMM: 128x64 tiles, 512 blocks (2/CU) ----------------
__global__ __launch_bounds__(256, 4) void gemm_out(const short* __restrict__ ah,
                                                   const short* __restrict__ WTo,
                                                   const float* __restrict__ bias,
                                                   float* __restrict__ Y) {
  __shared__ short AhL[8192], BhL[4096];
  const int bid = blockIdx.x;                      // 512
  const int nid = ((bid & 7) << 6) | (bid >> 3);   // XCD swizzle, bijective
  const int row0 = (nid >> 4) * 128, col0 = (nid & 15) * 64;
  const int lane = threadIdx.x & 63, wv = threadIdx.x >> 6;
  const int l15 = lane & 15, g = lane >> 4;

  const int r8 = lane >> 3;
  const int sch = ((lane & 7) ^ r8) << 3;
  size_t aoff[4], boff[2];
#pragma unroll
  for (int gi = 0; gi < 4; ++gi)
    aoff[gi] = (size_t)(row0 + wv * 32 + 8 * gi + r8) * Cc + sch;
#pragma unroll
  for (int gi = 0; gi < 2; ++gi)
    boff[gi] = (size_t)(col0 + wv * 16 + 8 * gi + r8) * Cc + sch;
  short* dA = AhL + wv * 2048;
  short* dB = BhL + wv * 1024;

  int aL[2][2], bL[4][2];
#pragma unroll
  for (int m = 0; m < 2; ++m)
#pragma unroll
    for (int s = 0; s < 2; ++s)
      aL[m][s] = (wv * 32 + m * 16 + l15) * 64 + (((4 * s + g) ^ (l15 & 7)) << 3);
#pragma unroll
  for (int n = 0; n < 4; ++n)
#pragma unroll
    for (int s = 0; s < 2; ++s)
      bL[n][s] = (n * 16 + l15) * 64 + (((4 * s + g) ^ (l15 & 7)) << 3);

  f32x4 acc[2][4];
#pragma unroll
  for (int m = 0; m < 2; ++m)
#pragma unroll
    for (int n = 0; n < 4; ++n) acc[m][n] = (f32x4){0.f, 0.f, 0.f, 0.f};

  for (int k0 = 0; k0 < Cc; k0 += 64) {
    __syncthreads();
#pragma unroll
    for (int gi = 0; gi < 4; ++gi) gll16(ah + aoff[gi] + k0, dA + gi * 512);
#pragma unroll
    for (int gi = 0; gi < 2; ++gi) gll16(WTo + boff[gi] + k0, dB + gi * 512);
    __syncthreads();
#pragma unroll
    for (int s = 0; s < 2; ++s) {
      half8v a[2], b[4];
#pragma unroll
      for (int m = 0; m < 2; ++m) a[m] = __builtin_bit_cast(half8v, *(short8v*)&AhL[aL[m][s]]);
#pragma unroll
      for (int n = 0; n < 4; ++n) b[n] = __builtin_bit_cast(half8v, *(short8v*)&BhL[bL[n][s]]);
#pragma unroll
      for (int m = 0; m < 2; ++m)
#pragma unroll
        for (int n = 0; n < 4; ++n)
          acc[m][n] = __builtin_amdgcn_mfma_f32_16x16x32_f16(a[m], b[n], acc[m][n], 0, 0, 0);
    }
  }

#pragma unroll
  for (int n = 0; n < 4; ++n) {
    const int ccol = col0 + n * 16 + l15;
    const float b0 = bias[ccol];
#pragma unroll
    for (int m = 0; m < 2; ++m)
#pragma unroll
      for (int rr = 0; rr < 4; ++rr) {
        int R = row0 + wv * 32 + m * 16 + g * 4 + rr;
        Y[(size_t)R * Cc + ccol] = acc[m][n][rr] + b0;
      }
  }
}

// ================= MFMA flash attention: split-K=2 (r18 structure) =================
// 32 jobs/bh, grid 1024 = 4 blocks/CU; decode bhj=t7&3, j=t7>>2 balances CUs.
// kh=0 -> ah (strided fp16); kh=1 -> dense fp16 partial p1; side[kh]=l.
static __device__ const int JQ2[32] = {0,0, 1,1, 2,2, 3,3, 4,4, 5,5, 6,6, 7,7,
                                       8,8, 9,9, 10,10, 11,11, 12,12, 13,13,
                                       14,14, 15,15};
static __device__ const int JK2[32] = {0,1, 0,1, 0,1, 0,1, 0,1, 0,1, 0,1, 0,1,
                                       0,1, 0,1, 0,1, 0,1, 0,1, 0,1, 0,1, 0,1};

__global__ __launch_bounds__(256, 4) void attn_mfma(const short* __restrict__ q,
                                                    const short* __restrict__ k,
                                                    const short* __restrict__ vT,
                                                    short* __restrict__ ah,
                                                    short* __restrict__ p1,
                                                    float* __restrict__ side) {
  const int n = blockIdx.x;           // 1024
  const int xcd = n & 7;
  const int t7 = n >> 3;              // 0..127
  const int bhj = t7 & 3;
  const int j = t7 >> 2;              // 0..31
  const int bh = xcd * 4 + bhj;
  const int Q = JQ2[j];
  const int kh = JK2[j];
  const int q0 = Q * 128;

  const int tid = threadIdx.x;
  const int lane = tid & 63;
  const int wv = tid >> 6;
  const int l31 = lane & 31;
  const int hb = lane >> 5;
  const int qbase = q0 + wv * 32;
  const int tq = qbase + l31;

  const short* qgb = q + (size_t)bh * Tt * Dd;
  const short* kgb = k + (size_t)bh * Tt * Dd;
  const short* vgb = vT + (size_t)bh * Dd * Tt;

  const short* qp = qgb + (size_t)tq * Dd + 8 * hb;
  half8v qf[4];
#pragma unroll
  for (int i = 0; i < 4; ++i) qf[i] = __builtin_bit_cast(half8v, *(const short8v*)(qp + 16 * i));

  __shared__ short Klds[2][4096];
  __shared__ short Vt[2][4096];

  const int r8 = lane >> 3;
  const size_t ksrc0 = (size_t)(wv * 16 + r8) * Dd + (((lane & 7) ^ r8) << 3);
  const size_t ksrc1 = ksrc0 + (size_t)8 * Dd;
  const int vlog = ((lane & 7) - r8) & 7;
  const size_t vsrc0 = (size_t)(wv * 16 + r8) * Tt + (vlog << 3);
  const size_t vsrc1 = vsrc0 + (size_t)8 * Tt;

#define STAGE64(BUF, JT)                                                     \
  {                                                                          \
    gll16(kgb + (size_t)(JT) * Dd + ksrc0, &Klds[BUF][wv * 1024]);           \
    gll16(kgb + (size_t)(JT) * Dd + ksrc1, &Klds[BUF][wv * 1024 + 512]);     \
    gll16(vgb + vsrc0 + (JT), &Vt[BUF][wv * 1024]);                          \
    gll16(vgb + vsrc1 + (JT), &Vt[BUF][wv * 1024 + 512]);                    \
  }

  int koff[4], voff[4];
#pragma unroll
  for (int i = 0; i < 4; ++i) {
    koff[i] = l31 * 64 + (((2 * i + hb) ^ (l31 & 7)) << 3);
    voff[i] = l31 * 64 + ((((2 * i + hb) + (l31 & 7)) & 7) << 3);
  }

  f32x16 oacc[2];
#pragma unroll
  for (int t = 0; t < 2; ++t)
#pragma unroll
    for (int r = 0; r < 16; ++r) oacc[t][r] = 0.f;
  float lrun = 0.f;

  const int cs0 = (q0 >= 512) ? (q0 - 511) : 0;
  const int cstart = cs0 & ~63;
  const int nch_b = (Tt - cstart) >> 6;
  const int lower = (nch_b + 1) >> 1;
  const int mystart = cstart + (kh ? (lower << 6) : 0);
  const int myn = kh ? (nch_b - lower) : lower;

  STAGE64(0, mystart);
  __syncthreads();

  int cur = 0;
  for (int ci = 0; ci < myn; ++ci) {
    const int jt = mystart + (ci << 6);

    if (ci + 1 < myn) STAGE64(cur ^ 1, jt + 64);

    const short* kbuf = &Klds[cur][0];
    f32x16 seA, seB;
#pragma unroll
    for (int r = 0; r < 16; ++r) { seA[r] = 0.f; seB[r] = 0.f; }
    __builtin_amdgcn_s_setprio(1);
#pragma unroll
    for (int i = 0; i < 4; ++i) {
      half8v kfA = __builtin_bit_cast(half8v, *(short8v*)&kbuf[koff[i]]);
      seA = __builtin_amdgcn_mfma_f32_32x32x16_f16(kfA, qf[i], seA, 0, 0, 0);
    }
#pragma unroll
    for (int i = 0; i < 4; ++i) {
      half8v kfB = __builtin_bit_cast(half8v, *(short8v*)&kbuf[koff[i] + 2048]);
      seB = __builtin_amdgcn_mfma_f32_32x32x16_f16(kfB, qf[i], seB, 0, 0, 0);
    }
    __builtin_amdgcn_s_setprio(0);

    if (jt < qbase - 480) {
      int th = tq - 511 - jt;
#pragma unroll
      for (int r = 0; r < 16; ++r) {
        int row = (r & 3) + 8 * (r >> 2) + 4 * hb;
        if (row < th) seA[r] = -1e30f;
        if (32 + row < th) seB[r] = -1e30f;
      }
    }

    float pA[16], pB[16];
#pragma unroll
    for (int r = 0; r < 16; ++r) {
      asm("v_exp_f32 %0, %1" : "=v"(pA[r]) : "v"(seA[r]));
      asm("v_exp_f32 %0, %1" : "=v"(pB[r]) : "v"(seB[r]));
    }
    float t0 = 0.f, t1 = 0.f, t2 = 0.f, t3 = 0.f;
#pragma unroll
    for (int r = 0; r < 16; r += 4) {
      t0 += pA[r];     t1 += pA[r + 1]; t2 += pA[r + 2]; t3 += pA[r + 3];
      t0 += pB[r];     t1 += pB[r + 1]; t2 += pB[r + 2]; t3 += pB[r + 3];
    }
    float psum = (t0 + t1) + (t2 + t3);
    psum += __shfl_xor(psum, 32);
    lrun += psum;

    unsigned pa[8], pb[8];
#pragma unroll
    for (int i = 0; i < 8; ++i) {
      pa[i] = __builtin_bit_cast(unsigned, __builtin_amdgcn_cvt_pkrtz(pA[2 * i], pA[2 * i + 1]));
      pb[i] = __builtin_bit_cast(unsigned, __builtin_amdgcn_cvt_pkrtz(pB[2 * i], pB[2 * i + 1]));
    }
    asm volatile("v_permlane32_swap_b32 %0, %1" : "+v"(pa[0]), "+v"(pa[2]));
    asm volatile("v_permlane32_swap_b32 %0, %1" : "+v"(pa[1]), "+v"(pa[3]));
    asm volatile("v_permlane32_swap_b32 %0, %1" : "+v"(pa[4]), "+v"(pa[6]));
    asm volatile("v_permlane32_swap_b32 %0, %1" : "+v"(pa[5]), "+v"(pa[7]));
    asm volatile("v_permlane32_swap_b32 %0, %1" : "+v"(pb[0]), "+v"(pb[2]));
    asm volatile("v_permlane32_swap_b32 %0, %1" : "+v"(pb[1]), "+v"(pb[3]));
    asm volatile("v_permlane32_swap_b32 %0, %1" : "+v"(pb[4]), "+v"(pb[6]));
    asm volatile("v_permlane32_swap_b32 %0, %1" : "+v"(pb[5]), "+v"(pb[7]));
    uint4v fA0, fA1, fB0, fB1;
    fA0[0] = pa[0]; fA0[1] = pa[1]; fA0[2] = pa[2]; fA0[3] = pa[3];
    fA1[0] = pa[4]; fA1[1] = pa[5]; fA1[2] = pa[6]; fA1[3] = pa[7];
    fB0[0] = pb[0]; fB0[1] = pb[1]; fB0[2] = pb[2]; fB0[3] = pb[3];
    fB1[0] = pb[4]; fB1[1] = pb[5]; fB1[2] = pb[6]; fB1[3] = pb[7];
    half8v pfA0 = __builtin_bit_cast(half8v, fA0);
    half8v pfA1 = __builtin_bit_cast(half8v, fA1);
    half8v pfB0 = __builtin_bit_cast(half8v, fB0);
    half8v pfB1 = __builtin_bit_cast(half8v, fB1);

    const short* vbuf = &Vt[cur][0];
    __builtin_amdgcn_s_setprio(1);
#pragma unroll
    for (int t = 0; t < 2; ++t) {
      const int ro = t * 2048;
      half8v v0 = __builtin_bit_cast(half8v, *(short8v*)&vbuf[voff[0] + ro]);
      half8v v1 = __builtin_bit_cast(half8v, *(short8v*)&vbuf[voff[1] + ro]);
      half8v v2 = __builtin_bit_cast(half8v, *(short8v*)&vbuf[voff[2] + ro]);
      half8v v3 = __builtin_bit_cast(half8v, *(short8v*)&vbuf[voff[3] + ro]);
      oacc[t] = __builtin_amdgcn_mfma_f32_32x32x16_f16(v0, pfA0, oacc[t], 0, 0, 0);
      oacc[t] = __builtin_amdgcn_mfma_f32_32x32x16_f16(v1, pfA1, oacc[t], 0, 0, 0);
      oacc[t] = __builtin_amdgcn_mfma_f32_32x32x16_f16(v2, pfB0, oacc[t], 0, 0, 0);
      oacc[t] = __builtin_amdgcn_mfma_f32_32x32x16_f16(v3, pfB1, oacc[t], 0, 0, 0);
    }
    __builtin_amdgcn_s_setprio(0);

    __syncthreads();
    cur ^= 1;
  }

  // ---- epilogue: kh=0 -> ah strided; kh=1 -> dense fp16 partial p1 ----
  const float invl = 1.f / lrun;
  const int row = bh * Tt + tq;
  if (hb == 0) side[kh * 65536 + row] = lrun;
  const int bI = bh >> 4, hd = bh & 15;
  if (kh == 0) {
    short* op = ah + ((size_t)(bI * Tt + tq)) * Cc + hd * Dd;
#pragma unroll
    for (int t = 0; t < 2; ++t)
#pragma unroll
      for (int rq = 0; rq < 4; ++rq) {
        short4v hv;
#pragma unroll
        for (int rr = 0; rr < 4; ++rr) hv[rr] = f2h(oacc[t][4 * rq + rr] * invl);
        *(short4v*)(op + 32 * t + 8 * rq + 4 * hb) = hv;
      }
  } else {
    short* pp = p1 + (size_t)row * 64;
#pragma unroll
    for (int t = 0; t < 2; ++t)
#pragma unroll
      for (int rq = 0; rq < 4; ++rq) {
        short4v hv;
#pragma unroll
        for (int rr = 0; rr < 4; ++rr) hv[rr] = f2h(oacc[t][4 * rq + rr] * invl);
        *(short4v*)(pp + 32 * t + 8 * rq + 4 * hb) = hv;
      }
  }
}

// ---------------- merge the two key-halves (all rows, fp16 partial) ----------------
__global__ __launch_bounds__(256) void attn_merge(short* __restrict__ ah,
                                                  const short* __restrict__ p1,
                                                  const float* __restrict__ side) {
  const int bh = blockIdx.y;                         // 0..31
  const int idx = blockIdx.x * 256 + threadIdx.x;    // [0, 8192)
  const int tq = idx >> 2;                           // [0, 2048)
  const int qd = (idx & 3) << 4;
  const int row = bh * Tt + tq;
  const float l0 = side[row], l1 = side[65536 + row];
  const float inv = 1.f / (l0 + l1);
  const float a0 = l0 * inv, a1 = l1 * inv;

  const int bI = bh >> 4, hd = bh & 15;
  short* op = ah + ((size_t)(bI * Tt + tq)) * Cc + hd * Dd + qd;
  const short* r1 = p1 + (size_t)row * 64 + qd;

  short8v h0 = *(short8v*)op,        h1 = *(short8v*)(op + 8);
  short8v u0 = *(const short8v*)r1,  u1 = *(const short8v*)(r1 + 8);
  short8v o0, o1;
#pragma unroll
  for (int e = 0; e < 8; ++e) o0[e] = f2h(a0 * h2f(h0[e]) + a1 * h2f(u0[e]));
#pragma unroll
  for (int e = 0; e < 8; ++e) o1[e] = f2h(a0 * h2f(h1[e]) + a1 * h2f(u1[e]));
  *(short8v*)op = o0;
  *(short8v*)(op + 8) = o1;
}

extern "C" void kernel_launch(void* const* d_in, const int* in_sizes, int n_in,
                              void* d_out, int out_size, void* d_ws, size_t ws_size,
                              hipStream_t stream) {
  const float* x  = (const float*)d_in[0];
  const float* Wq = (const float*)d_in[1];
  const float* bq = (const float*)d_in[2];
  const float* Wk = (const float*)d_in[3];
  const float* bk = (const float*)d_in[4];
  const float* Wv = (const float*)d_in[5];
  const float* bv = (const float*)d_in[6];
  const float* Wo = (const float*)d_in[7];
  const float* bo = (const float*)d_in[8];

  short* ws16 = (short*)d_ws;
  short* xh  = ws16;                  // 8MB fp16 x
  short* WTh = ws16 + 4194304;        // 8MB: Wq,Wk,Wv,Wo transposed fp16
  short* qb  = ws16 + 8388608;        // 8MB fp16 [B,H,T,D]
  short* kb  = ws16 + 12582912;       // 8MB fp16 [B,H,T,D]
  short* vb  = ws16 + 16777216;       // 8MB fp16 [B,H,D,T] (V transposed)
  short* ah  = ws16 + 20971520;       // 8MB fp16 attn out [B,T,C]
  short* p1  = ws16 + 25165824;       // 8MB fp16 kh=1 partial [65536][64]
  float* side = (float*)(ws16 + 29360128); // 0.5MB: [kh][65536] = l
  float* rt   = side + 131072;             // 0.5MB rope table [2048][32] float2

  prep<<<3328, 256, 0, stream>>>(x, Wq, Wk, Wv, Wo, xh, WTh, rt);

  gemm_qkv<<<dim3(256, 3), 256, 0, stream>>>(xh, WTh, bq, bk, bv, rt, qb, kb, vb);

  attn_mfma<<<1024, 256, 0, stream>>>(qb, kb, vb, ah, p1, side);
  attn_merge<<<dim3(32, 32), 256, 0, stream>>>(ah, p1, side);

  gemm_out<<<512, 256, 0, stream>>>(ah, WTh + 3 * 1048576, bo, (float*)d_out);
}